// Round 11
// baseline (252.381 us; speedup 1.0000x reference)
//
#include <hip/hip_runtime.h>

// Problem constants
#define BB     512
#define L1     16384
#define L2     2048
#define CL     14337      // conv_len = L1 - L2 + 1
#define NCC    28673      // 2*CL - 1 (number of cc lags)
#define PADL   14336      // CL - 1
#define CROW   14340      // padded conv row stride (floats, %4==0)
#define CROP   256
#define CSTART 7040       // (CL - CROP)/2
#define TLEN   14337      // target row length
#define FM     16384      // complex FFT size
#define LOGM   14

// Padded LDS indexing: phys = i + (i>>4).
#define NPAD  17408       // 16384 + 16384/16
#define IDX(i) ((i) + ((i) >> 4))
// For digit-aligned offsets (base%16 + off%16 <= 15): IDX(base+off) ==
// IDX(base) + PADOFF(off) exactly, with PADOFF compile-time (verified per-S).
#define PADOFF(o) ((o) + ((o) >> 4))

// base-4 digit reversal of a 14-bit index (7 digits)
__device__ __forceinline__ int rev4_14(int x) {
  int b = (int)(__brev((unsigned)x) >> 18);
  return ((b & 0x1555) << 1) | ((b >> 1) & 0x1555);
}

__device__ __forceinline__ unsigned int fkey(float f) {
  unsigned int b = __float_as_uint(f);
  return b ^ ((b & 0x80000000u) ? 0xFFFFFFFFu : 0x80000000u);  // order-preserving
}

__device__ __forceinline__ float blockReduceSum256(float v) {
  #pragma unroll
  for (int o = 32; o > 0; o >>= 1) v += __shfl_down(v, o, 64);
  __shared__ float sws[4];
  if ((threadIdx.x & 63) == 0) sws[threadIdx.x >> 6] = v;
  __syncthreads();
  float r = 0.f;
  if (threadIdx.x == 0) r = sws[0] + sws[1] + sws[2] + sws[3];
  return r;
}

// ---------------- complex helpers -------------------------------------------
__device__ __forceinline__ float2 cmul(const float2 w, const float2 u) {
  return make_float2(w.x * u.x - w.y * u.y, w.x * u.y + w.y * u.x);
}
__device__ __forceinline__ float2 cmulc(const float2 x, const float2 w) {  // x*conj(w)
  return make_float2(w.x * x.x + w.y * x.y, w.x * x.y - w.y * x.x);
}

__device__ __forceinline__ void bf4_dif(float2& x0, float2& x1, float2& x2, float2& x3) {
  float t0r = x0.x + x2.x, t0i = x0.y + x2.y;
  float t1r = x1.x + x3.x, t1i = x1.y + x3.y;
  float t2r = x0.x - x2.x, t2i = x0.y - x2.y;
  float t3r = x1.y - x3.y, t3i = x3.x - x1.x;   // -i*(x1-x3)
  x0 = make_float2(t0r + t1r, t0i + t1i);
  x1 = make_float2(t2r + t3r, t2i + t3i);
  x2 = make_float2(t0r - t1r, t0i - t1i);
  x3 = make_float2(t2r - t3r, t2i - t3i);
}

__device__ __forceinline__ void bf4_dit(float2& x0, float2& x1, float2& x2, float2& x3) {
  float s0r = x0.x + x2.x, s0i = x0.y + x2.y;
  float s1r = x0.x - x2.x, s1i = x0.y - x2.y;
  float s2r = x1.x + x3.x, s2i = x1.y + x3.y;
  float s3r = x3.y - x1.y, s3i = x1.x - x3.x;   // i*(x1-x3)
  x0 = make_float2(s0r + s2r, s0i + s2i);
  x1 = make_float2(s1r + s3r, s1i + s3i);
  x2 = make_float2(s0r - s2r, s0i - s2i);
  x3 = make_float2(s1r - s3r, s1i - s3i);
}

// ---------------- radix-16 phase FFT cores (512 threads, padded LDS) ---------
// R7 structure (proven: 128 VGPR) + PADOFF base+immediate addressing.
// 1024-thread variants are dead: compiler pins VGPR=64 and spills (R5/R6/R8).
template <int S>
__device__ __forceinline__ void fft_dif4_pair(float2* A, const float2* __restrict__ tw,
                                              int tid) {
  __syncthreads();
  constexpr int Q  = 1 << (2 * S - 2);
  constexpr int TS = 12 - 2 * S;
  #pragma unroll 1
  for (int r = 0; r < 2; ++r) {
    const int bf = (r << 9) | tid;
    const int jq = bf & (Q - 1);
    const int hi = bf >> (2 * S - 2);
    const int pb = IDX((hi << (2 * S + 2)) | jq);
    float2 x[4][4];   // x[a][b] at base + a*4^S + b*4^(S-1)
    #pragma unroll
    for (int a = 0; a < 4; ++a)
      #pragma unroll
      for (int b = 0; b < 4; ++b)
        x[a][b] = A[pb + PADOFF((a << (2 * S)) + (b << (2 * S - 2)))];
    // stage S over a (twiddle j = b*Q + jq)
    #pragma unroll
    for (int b = 0; b < 4; ++b) {
      bf4_dif(x[0][b], x[1][b], x[2][b], x[3][b]);
      const int jt = (b * Q + jq) << TS;
      x[1][b] = cmul(tw[jt],     x[1][b]);
      x[2][b] = cmul(tw[2 * jt], x[2][b]);
      x[3][b] = cmul(tw[3 * jt], x[3][b]);
    }
    // stage S-1 over b (twiddle j2 = jq, shared across a)
    const int jt2 = jq << (14 - 2 * S);
    const float2 v1 = tw[jt2], v2 = tw[2 * jt2], v3 = tw[3 * jt2];
    #pragma unroll
    for (int a = 0; a < 4; ++a) {
      bf4_dif(x[a][0], x[a][1], x[a][2], x[a][3]);
      x[a][1] = cmul(v1, x[a][1]);
      x[a][2] = cmul(v2, x[a][2]);
      x[a][3] = cmul(v3, x[a][3]);
    }
    #pragma unroll
    for (int a = 0; a < 4; ++a)
      #pragma unroll
      for (int b = 0; b < 4; ++b)
        A[pb + PADOFF((a << (2 * S)) + (b << (2 * S - 2)))] = x[a][b];
  }
}

// Final DIF stage s=0 (twiddles == 1). i0%16 in {0,4,8,12} -> IDX(i0)+j exact.
__device__ __forceinline__ void fft_dif4_last(float2* A, int tid) {
  __syncthreads();
  for (int r = 0; r < 8; ++r) {
    const int p0 = IDX((((r << 9) | tid) << 2));
    float2 x0 = A[p0], x1 = A[p0 + 1], x2 = A[p0 + 2], x3 = A[p0 + 3];
    bf4_dif(x0, x1, x2, x3);
    A[p0] = x0; A[p0 + 1] = x1; A[p0 + 2] = x2; A[p0 + 3] = x3;
  }
}

// First DIT stage s=0 (twiddles == 1)
__device__ __forceinline__ void fft_dit4_first(float2* A, int tid) {
  __syncthreads();
  for (int r = 0; r < 8; ++r) {
    const int p0 = IDX((((r << 9) | tid) << 2));
    float2 x0 = A[p0], x1 = A[p0 + 1], x2 = A[p0 + 2], x3 = A[p0 + 3];
    bf4_dit(x0, x1, x2, x3);
    A[p0] = x0; A[p0 + 1] = x1; A[p0 + 2] = x2; A[p0 + 3] = x3;
  }
}

// Merged DIT stage pair (S, S+1), S in {1,3,5}
template <int S>
__device__ __forceinline__ void fft_dit4_pair(float2* A, const float2* __restrict__ tw,
                                              int tid) {
  __syncthreads();
  constexpr int M = 1 << (2 * S);
  #pragma unroll 1
  for (int r = 0; r < 2; ++r) {
    const int bf = (r << 9) | tid;
    const int jq = bf & (M - 1);
    const int hi = bf >> (2 * S);
    const int pb = IDX((hi << (2 * S + 4)) | jq);
    float2 x[4][4];   // x[a][b] at base + b*4M + a*M
    #pragma unroll
    for (int a = 0; a < 4; ++a)
      #pragma unroll
      for (int b = 0; b < 4; ++b)
        x[a][b] = A[pb + PADOFF((b << (2 * S + 2)) + (a << (2 * S)))];
    // stage S over a: j = jq (same twiddles for all b)
    const int jt = jq << (12 - 2 * S);
    const float2 w1 = tw[jt], w2 = tw[2 * jt], w3 = tw[3 * jt];
    #pragma unroll
    for (int b = 0; b < 4; ++b) {
      x[1][b] = cmulc(x[1][b], w1);
      x[2][b] = cmulc(x[2][b], w2);
      x[3][b] = cmulc(x[3][b], w3);
      bf4_dit(x[0][b], x[1][b], x[2][b], x[3][b]);
    }
    // stage S+1 over b: j' = a*M + jq
    #pragma unroll
    for (int a = 0; a < 4; ++a) {
      const int jt2 = (a * M + jq) << (10 - 2 * S);
      x[a][1] = cmulc(x[a][1], tw[jt2]);
      x[a][2] = cmulc(x[a][2], tw[2 * jt2]);
      x[a][3] = cmulc(x[a][3], tw[3 * jt2]);
      bf4_dit(x[a][0], x[a][1], x[a][2], x[a][3]);
    }
    #pragma unroll
    for (int a = 0; a < 4; ++a)
      #pragma unroll
      for (int b = 0; b < 4; ++b)
        A[pb + PADOFF((b << (2 * S + 2)) + (a << (2 * S)))] = x[a][b];
  }
}

// DIF forward: natural-order input -> base-4 digit-reversed output (Y[k] at rev4_14(k))
__device__ __forceinline__ void fft_dif4(float2* A, const float2* __restrict__ tw, int tid) {
  fft_dif4_pair<6>(A, tw, tid);
  fft_dif4_pair<4>(A, tw, tid);
  fft_dif4_pair<2>(A, tw, tid);
  fft_dif4_last(A, tid);
  __syncthreads();
}

// DIT inverse (conjugate twiddles, unnormalized): digit-reversed input -> natural output
__device__ __forceinline__ void fft_dit4_inv(float2* A, const float2* __restrict__ tw, int tid) {
  fft_dit4_first(A, tid);
  fft_dit4_pair<1>(A, tw, tid);
  fft_dit4_pair<3>(A, tw, tid);
  fft_dit4_pair<5>(A, tw, tid);
  __syncthreads();
}

// ---- common small kernels ---------------------------------------------------

__global__ void init_kernel(unsigned long long* best, float* acc) {
  int i = blockIdx.x * blockDim.x + threadIdx.x;
  if (i < BB) best[i] = 0ull;
  if (i < 4)  acc[i]  = 0.f;
}

__global__ void twid_kernel(float2* tw, float2* w32) {
  int i = blockIdx.x * 256 + threadIdx.x;
  if (i < FM) {
    double a = -2.0 * 3.14159265358979323846 * (double)i / (double)FM;
    tw[i] = make_float2((float)cos(a), (float)sin(a));
  }
  if (i < 8192) {
    double a = -2.0 * 3.14159265358979323846 * (double)i / (double)(2 * FM);
    w32[i] = make_float2((float)cos(a), (float)sin(a));
  }
}

__global__ void astf_kernel(const float* __restrict__ p, const float* __restrict__ t,
                            float* __restrict__ acc) {
  int gid = blockIdx.x * blockDim.x + threadIdx.x;
  int stride = gridDim.x * blockDim.x;
  const float4* p4 = (const float4*)p;
  const float4* t4 = (const float4*)t;
  const int n4 = (BB * L1) / 4;
  float s = 0.f;
  for (int i = gid; i < n4; i += stride) {
    float4 a = p4[i], b = t4[i];
    float dx = a.x - b.x, dy = a.y - b.y, dz = a.z - b.z, dw = a.w - b.w;
    s += dx * dx + dy * dy + dz * dz + dw * dw;
  }
  s = blockReduceSum256(s);
  if (threadIdx.x == 0) atomicAdd(&acc[0], s);
}

// ---- FUSED FFT pipeline: astf-MSE + conv (circ corr @16384) + cc (rfft-32768)
// One block handles 2 batches end-to-end. New in R11:
//  - astf MSE fused into the conv pack loop (pred row is read anyway; true row
//    added; one 512-thread reduce + one atomic per block) -> astf_kernel gone.
//  - conv row repack to even/odd pairs is register-staged from LDS (28 floats,
//    FULLY unrolled so v[] stays in registers), with the global conv store
//    fused into the read pass -> no global re-read of conv (was 29.4 MB).
__global__ __launch_bounds__(512, 2) void pipefft_kernel(const float* __restrict__ pred,
                                                         const float* __restrict__ truea,
                                                         const float* __restrict__ egf,
                                                         const float* __restrict__ target,
                                                         const float2* __restrict__ tw,
                                                         const float2* __restrict__ w32,
                                                         float* convbuf,
                                                         float4* __restrict__ spec,
                                                         unsigned long long* __restrict__ best,
                                                         float* __restrict__ acc) {
  __shared__ float2 A[NPAD];
  __shared__ unsigned long long sbest[8];
  __shared__ float swsum[8];
  const int tid = threadIdx.x;
  float4* sp = spec + (size_t)blockIdx.x * 8192;
  float asum = 0.f;

  for (int half = 0; half < 2; ++half) {
    const int b = blockIdx.x * 2 + half;
    const float* pb = pred  + (size_t)b * L1;
    const float* tb = truea + (size_t)b * L1;
    const float* eb = egf   + (size_t)b * L2;
    float* cr       = convbuf + (size_t)b * CROW;
    const float* tr = target  + (size_t)b * TLEN;

    // ===== conv pack (+ fused astf MSE): z = pred + i*egf ====================
    for (int i = tid; i < FM; i += 512) {
      float pv = pb[i];
      float d  = pv - tb[i];
      asum += d * d;
      A[IDX(i)] = make_float2(pv, (i < L2) ? eb[i] : 0.f);
    }

    fft_dif4(A, tw, tid);

    for (int rr = 0; rr < 16; ++rr) {
      const int k = tid * 16 + rr;
      if (k == 0) {
        float2 z0 = A[IDX(0)];
        A[IDX(0)] = make_float2(z0.x * z0.y, 0.f);
        const int p = IDX(2);                 // rev4(8192) == 2
        float2 zn = A[p];
        A[p] = make_float2(zn.x * zn.y, 0.f);
      } else {
        const int p = IDX(rev4_14(k)), q = IDX(rev4_14(FM - k));
        float2 z1 = A[p], z2 = A[q];
        float pr = 0.5f * (z1.x + z2.x), pi = 0.5f * (z1.y - z2.y);   // PRED[k]
        float er = 0.5f * (z1.y + z2.y), ei = 0.5f * (z2.x - z1.x);   // EGF[k]
        float sr = pr * er + pi * ei;                                  // S = PRED*conj(EGF)
        float si = pi * er - pr * ei;
        A[p] = make_float2(sr, si);
        A[q] = make_float2(sr, -si);
      }
    }

    fft_dit4_inv(A, tw, tid);   // A[IDX(n)].x = conv[n]*FM, natural order

    // ===== register-staged repack: store conv row + build x[i]=(c[2i],c[2i+1])
    // Reads A[IDX(2i)].x / A[IDX(2i)+1].x (adjacent: 2i%16<=14). FULL unroll so
    // v[] is statically indexed (registers, not scratch).
    const float sc = 1.f / (float)FM;
    float2 v[15];
    #pragma unroll
    for (int r = 0; r < 14; ++r) {
      const int i = tid + (r << 9);           // i <= 7167: both elems < CL-1
      const int p = IDX(2 * i);
      float c0 = A[p].x * sc, c1 = A[p + 1].x * sc;
      *(float2*)(cr + 2 * i) = make_float2(c0, c1);
      v[r] = make_float2(c0, c1);
    }
    {
      // r=14: only i==7168 (tid 0) nonzero: x[7168]=(conv[14336], 0)
      float c0 = 0.f;
      if (tid == 0) {
        c0 = A[IDX(14336)].x * sc;
        cr[14336] = c0;
      }
      v[14] = make_float2(c0, 0.f);
    }
    __syncthreads();   // all LDS reads done before overwrite

    #pragma unroll
    for (int r = 0; r < 15; ++r) {
      const int i = tid + (r << 9);
      A[IDX(i)] = v[r];
    }
    for (int i = tid + 7680; i < FM; i += 512)  // r=15 region + upper half
      A[IDX(i)] = make_float2(0.f, 0.f);

    fft_dif4(A, tw, tid);                       // Yc of packed conv

    // stash Yc in glue order (coalesced float4): sp[(rr<<9)|tid] =
    // (Yc[rev4(k)], Yc[rev4(FM-k)]) for k = tid*16+rr; (0,8192) in k==0 slot
    #pragma unroll 1
    for (int rr = 0; rr < 16; ++rr) {
      const int k = tid * 16 + rr;
      const int s = (rr << 9) | tid;
      float2 ya, yb;
      if (k == 0) { ya = A[IDX(0)]; yb = A[IDX(2)]; }   // rev4(8192) == 2
      else        { ya = A[IDX(rev4_14(k))]; yb = A[IDX(rev4_14(FM - k))]; }
      sp[s] = make_float4(ya.x, ya.y, yb.x, yb.y);
    }
    __syncthreads();

    // target packed even/odd (TLEN odd -> rows misaligned for odd b; scalar)
    for (int i = tid; i < FM; i += 512) {
      int g = 2 * i;
      float re = (g     < TLEN) ? tr[g]     : 0.f;
      float im = (g + 1 < TLEN) ? tr[g + 1] : 0.f;
      A[IDX(i)] = make_float2(re, im);
    }
    fft_dif4(A, tw, tid);                                    // A = Yt

    // glue: build y' spectrum of the packed cc sequence, in digit-rev slots
    #pragma unroll 1
    for (int rr = 0; rr < 16; ++rr) {
      const int k = tid * 16 + rr;
      const int s = (rr << 9) | tid;
      const float4 y4 = sp[s];                        // coalesced
      if (k == 0) {
        float2 yc0 = make_float2(y4.x, y4.y), yt0 = A[IDX(0)];
        float X0 = yc0.x + yc0.y, XM = yc0.x - yc0.y;
        float T0 = yt0.x + yt0.y, TM = yt0.x - yt0.y;
        float C0 = X0 * T0, CM = XM * TM;
        A[IDX(0)] = make_float2(0.5f * (C0 + CM), 0.5f * (C0 - CM));
        // bin 8192 (self-paired): rev4(8192) == 2
        float2 yc = make_float2(y4.z, y4.w), yt = A[IDX(2)];
        float cr8 = yc.x * yt.x + yc.y * yt.y;
        float ci8 = yc.x * yt.y - yc.y * yt.x;
        A[IDX(2)] = make_float2(cr8, -ci8);
      } else {
        const int p = IDX(rev4_14(k)), q = IDX(rev4_14(FM - k));
        const float2 w = w32[k];                        // e^{-2*pi*i*k/32768}
        // X[k], X[M-k] from Yc (coalesced stash)
        float2 ya = make_float2(y4.x, y4.y), yb = make_float2(y4.z, y4.w);
        float xer = 0.5f * (ya.x + yb.x), xei = 0.5f * (ya.y - yb.y);
        float dr  = 0.5f * (ya.x - yb.x), di  = 0.5f * (ya.y + yb.y);
        float xo_r = di, xo_i = -dr;                    // Xo = -i*D
        float wxr = w.x * xo_r - w.y * xo_i, wxi = w.x * xo_i + w.y * xo_r;
        float Xkr = xer + wxr, Xki = xei + wxi;
        float Xmr = xer - wxr, Xmi = -(xei - wxi);      // X[M-k] = conj(Xe - W*Xo)
        // T[k], T[M-k] from Yt
        float2 ta = A[p], tb2 = A[q];
        float ter = 0.5f * (ta.x + tb2.x), tei = 0.5f * (ta.y - tb2.y);
        float er2 = 0.5f * (ta.x - tb2.x), ei2 = 0.5f * (ta.y + tb2.y);
        float to_r = ei2, to_i = -er2;
        float twr = w.x * to_r - w.y * to_i, twi = w.x * to_i + w.y * to_r;
        float Tkr = ter + twr, Tki = tei + twi;
        float Tmr = ter - twr, Tmi = -(tei - twi);
        // C[k]=X[k]*conj(T[k]); C[M-k]=X[M-k]*conj(T[M-k])
        float Ckr = Xkr * Tkr + Xki * Tki, Cki = Xki * Tkr - Xkr * Tki;
        float Cmr = Xmr * Tmr + Xmi * Tmi, Cmi = Xmi * Tmr - Xmr * Tmi;
        // y'[k] = Ce + i*V*D, V = conj(w)
        float aer = 0.5f * (Ckr + Cmr), aei = 0.5f * (Cki - Cmi);
        float bdr = 0.5f * (Ckr - Cmr), bdi = 0.5f * (Cki + Cmi);
        float cor_ = w.x * bdr + w.y * bdi, coi = w.x * bdi - w.y * bdr;
        A[p] = make_float2(aer - coi, aei + cor_);
        // y'[M-k] = Ce2 + i*(-w)*D2
        float a2r = 0.5f * (Cmr + Ckr), a2i = 0.5f * (Cmi - Cki);
        float d2r = 0.5f * (Cmr - Ckr), d2i = 0.5f * (Cmi + Cki);
        float c2r = -(w.x * d2r - w.y * d2i), c2i = -(w.x * d2i + w.y * d2r);
        A[q] = make_float2(a2r - c2i, a2i + c2r);
      }
    }

    fft_dit4_inv(A, tw, tid);  // A[n] = (cc[2n], cc[2n+1]) * FM

    // argmax with j->np mapping: j<=14336 -> np=j ; (14336,18432) dead ; j>=18432 -> np=j-4095
    unsigned long long pk = 0ull;
    for (int i = tid; i < FM; i += 512) {
      float2 v2 = A[IDX(i)];
      int j0 = 2 * i, j1 = 2 * i + 1;
      if (j0 <= 14336) {
        unsigned long long p = ((unsigned long long)fkey(v2.x) << 32)
                             | (unsigned long long)(0xFFFFFFFFu - (unsigned)j0);
        if (p > pk) pk = p;
      } else if (j0 >= 18432) {
        unsigned long long p = ((unsigned long long)fkey(v2.x) << 32)
                             | (unsigned long long)(0xFFFFFFFFu - (unsigned)(j0 - 4095));
        if (p > pk) pk = p;
      }
      if (j1 <= 14336) {
        unsigned long long p = ((unsigned long long)fkey(v2.y) << 32)
                             | (unsigned long long)(0xFFFFFFFFu - (unsigned)j1);
        if (p > pk) pk = p;
      } else if (j1 >= 18432) {
        unsigned long long p = ((unsigned long long)fkey(v2.y) << 32)
                             | (unsigned long long)(0xFFFFFFFFu - (unsigned)(j1 - 4095));
        if (p > pk) pk = p;
      }
    }
    #pragma unroll
    for (int o = 32; o > 0; o >>= 1) {
      unsigned long long q = __shfl_down(pk, o, 64);
      if (q > pk) pk = q;
    }
    if ((tid & 63) == 0) sbest[tid >> 6] = pk;
    __syncthreads();
    if (tid == 0) {
      #pragma unroll
      for (int i = 1; i < 8; ++i) if (sbest[i] > pk) pk = sbest[i];
      best[b] = pk;
    }
    __syncthreads();
  }

  // ===== fused astf MSE reduction (both halves), one atomic per block ========
  #pragma unroll
  for (int o = 32; o > 0; o >>= 1) asum += __shfl_down(asum, o, 64);
  if ((tid & 63) == 0) swsum[tid >> 6] = asum;
  __syncthreads();
  if (tid == 0) {
    float s = 0.f;
    #pragma unroll
    for (int i = 0; i < 8; ++i) s += swsum[i];
    atomicAdd(&acc[0], s);
  }
}

// ---- fallback direct path (proven r3 kernels) -------------------------------

__device__ __forceinline__ void taps4(float* acc, const float4 a, const float4 b,
                                      const float4 e) {
  acc[0] = fmaf(a.x, e.x, acc[0]); acc[0] = fmaf(a.y, e.y, acc[0]);
  acc[0] = fmaf(a.z, e.z, acc[0]); acc[0] = fmaf(a.w, e.w, acc[0]);
  acc[1] = fmaf(a.y, e.x, acc[1]); acc[1] = fmaf(a.z, e.y, acc[1]);
  acc[1] = fmaf(a.w, e.z, acc[1]); acc[1] = fmaf(b.x, e.w, acc[1]);
  acc[2] = fmaf(a.z, e.x, acc[2]); acc[2] = fmaf(a.w, e.y, acc[2]);
  acc[2] = fmaf(b.x, e.z, acc[2]); acc[2] = fmaf(b.y, e.w, acc[2]);
  acc[3] = fmaf(a.w, e.x, acc[3]); acc[3] = fmaf(b.x, e.y, acc[3]);
  acc[3] = fmaf(b.y, e.z, acc[3]); acc[3] = fmaf(b.z, e.w, acc[3]);
}

__device__ __forceinline__ float4 gload4(const float* __restrict__ cr, int g) {
  if (g >= 0 && g + 3 < CL) return *(const float4*)(cr + g);
  float4 v;
  int g0 = min(max(g,     0), CL - 1);
  int g1 = min(max(g + 1, 0), CL - 1);
  int g2 = min(max(g + 2, 0), CL - 1);
  int g3 = min(max(g + 3, 0), CL - 1);
  v.x = (g     >= 0 && g     < CL) ? cr[g0] : 0.f;
  v.y = (g + 1 >= 0 && g + 1 < CL) ? cr[g1] : 0.f;
  v.z = (g + 2 >= 0 && g + 2 < CL) ? cr[g2] : 0.f;
  v.w = (g + 3 >= 0 && g + 3 < CL) ? cr[g3] : 0.f;
  return v;
}

__global__ __launch_bounds__(256) void conv_kernel(const float* __restrict__ pred,
                                                   const float* __restrict__ egf,
                                                   float* __restrict__ convbuf) {
  const int b = blockIdx.y;
  const int x = blockIdx.x;
  const int tid = threadIdx.x;
  const float* pb = pred + (size_t)b * L1;
  const float* eg = egf  + (size_t)b * L2;
  float* cr = convbuf + (size_t)b * CROW;

  if (x == 7) {
    float s = 0.f;
    const int k0 = tid * 8;
    #pragma unroll
    for (int j = 0; j < 8; ++j) s += pb[PADL + k0 + j] * eg[k0 + j];
    s = blockReduceSum256(s);
    if (tid == 0) cr[PADL] = s;
    return;
  }

  const int m = x * 2048 + tid * 8;
  const float* cp = pb + m;
  float accA[4] = {0.f,0.f,0.f,0.f};
  float accB[4] = {0.f,0.f,0.f,0.f};
  float4 w0 = *(const float4*)(cp);
  float4 w1 = *(const float4*)(cp + 4);
  float4 w2 = *(const float4*)(cp + 8);

  #pragma unroll 4
  for (int k = 0; k < L2 - 4; k += 4) {
    const float4 e  = *(const float4*)(eg + k);
    const float4 nx = *(const float4*)(cp + k + 12);
    taps4(accA, w0, w1, e);
    taps4(accB, w1, w2, e);
    w0 = w1; w1 = w2; w2 = nx;
  }
  {
    const float4 e = *(const float4*)(eg + (L2 - 4));
    taps4(accA, w0, w1, e);
    taps4(accB, w1, w2, e);
  }

  *(float4*)(cr + m)     = make_float4(accA[0], accA[1], accA[2], accA[3]);
  *(float4*)(cr + m + 4) = make_float4(accB[0], accB[1], accB[2], accB[3]);
}

__global__ __launch_bounds__(256) void cc_kernel(const float* __restrict__ convbuf,
                                                 const float* __restrict__ target,
                                                 unsigned long long* __restrict__ best) {
  __shared__ unsigned long long sbest[4];
  const int b   = blockIdx.y;
  const int m0  = blockIdx.x * 2048;
  const int tid = threadIdx.x;
  const float* cr = convbuf + (size_t)b * CROW;
  const float* tr = target  + (size_t)b * TLEN;
  const int m    = m0 + tid * 8;
  const int gofs = m - PADL;

  float accA[4] = {0.f,0.f,0.f,0.f};
  float accB[4] = {0.f,0.f,0.f,0.f};

  const int t1raw = PADL - m0;
  const int t1    = t1raw > 0 ? t1raw : 0;
  const int t2    = PADL + CL - m0 - 2047;
  int tIntHi      = (t2 - 16) & ~3;
  if (tIntHi > 14332) tIntHi = 14332;
  if (tIntHi < t1)    tIntHi = t1;
  int e0 = (t1raw - 2047) > 0 ? ((t1raw - 2047) & ~3) : 0;
  const int eH = min(TLEN, NCC - m0);

  if (e0 < t1) {
    float4 w0 = gload4(cr, gofs + e0);
    float4 w1 = gload4(cr, gofs + e0 + 4);
    float4 w2 = gload4(cr, gofs + e0 + 8);
    #pragma unroll 2
    for (int t = e0; t < t1; t += 4) {
      const float4 e  = *(const float4*)(tr + t);
      const float4 nx = gload4(cr, gofs + t + 12);
      taps4(accA, w0, w1, e);
      taps4(accB, w1, w2, e);
      w0 = w1; w1 = w2; w2 = nx;
    }
  }

  if (t1 < tIntHi) {
    const float* cp = cr + gofs;
    float4 w0 = *(const float4*)(cp + t1);
    float4 w1 = *(const float4*)(cp + t1 + 4);
    float4 w2 = *(const float4*)(cp + t1 + 8);
    #pragma unroll 4
    for (int t = t1; t < tIntHi; t += 4) {
      const float4 e  = *(const float4*)(tr + t);
      const float4 nx = *(const float4*)(cp + t + 12);
      taps4(accA, w0, w1, e);
      taps4(accB, w1, w2, e);
      w0 = w1; w1 = w2; w2 = nx;
    }
  }

  if (tIntHi < eH) {
    float4 w0 = gload4(cr, gofs + tIntHi);
    float4 w1 = gload4(cr, gofs + tIntHi + 4);
    float4 w2 = gload4(cr, gofs + tIntHi + 8);
    #pragma unroll 2
    for (int t = tIntHi; t < eH; t += 4) {
      float4 e;
      e.x = (t     < TLEN) ? tr[t]     : 0.f;
      e.y = (t + 1 < TLEN) ? tr[t + 1] : 0.f;
      e.z = (t + 2 < TLEN) ? tr[t + 2] : 0.f;
      e.w = (t + 3 < TLEN) ? tr[t + 3] : 0.f;
      const float4 nx = gload4(cr, gofs + t + 12);
      taps4(accA, w0, w1, e);
      taps4(accB, w1, w2, e);
      w0 = w1; w1 = w2; w2 = nx;
    }
  }

  unsigned long long pk = 0ull;
  #pragma unroll
  for (int j = 0; j < 4; ++j) {
    int mm = m + j;
    if (mm < NCC) {
      int np = (mm >= PADL) ? (mm - PADL) : (mm + CL);
      unsigned long long p = ((unsigned long long)fkey(accA[j]) << 32)
                           | (unsigned long long)(0xFFFFFFFFu - (unsigned)np);
      if (p > pk) pk = p;
    }
    mm = m + 4 + j;
    if (mm < NCC) {
      int np = (mm >= PADL) ? (mm - PADL) : (mm + CL);
      unsigned long long p = ((unsigned long long)fkey(accB[j]) << 32)
                           | (unsigned long long)(0xFFFFFFFFu - (unsigned)np);
      if (p > pk) pk = p;
    }
  }
  #pragma unroll
  for (int o = 32; o > 0; o >>= 1) {
    unsigned long long q = __shfl_down(pk, o, 64);
    if (q > pk) pk = q;
  }
  if ((tid & 63) == 0) sbest[tid >> 6] = pk;
  __syncthreads();
  if (tid == 0) {
    #pragma unroll
    for (int i = 1; i < 4; ++i) if (sbest[i] > pk) pk = sbest[i];
    atomicMax(best + b, pk);
  }
}

__global__ void closs_kernel(const float* __restrict__ convbuf,
                             const float* __restrict__ target,
                             const unsigned long long* __restrict__ best,
                             float* __restrict__ acc) {
  const int b = blockIdx.x;
  const int np = (int)(0xFFFFFFFFu - (unsigned)(best[b] & 0xFFFFFFFFull));
  const int shift = np - PADL;
  const int jj = CSTART + threadIdx.x;
  int pos = jj + shift;
  if (pos < 0) pos += CL; else if (pos >= CL) pos -= CL;
  float d = convbuf[(size_t)b * CROW + pos] - target[(size_t)b * TLEN + jj];
  float s = blockReduceSum256(d * d);
  if (threadIdx.x == 0) atomicAdd(&acc[1], s);
}

__global__ void fin_kernel(const float* __restrict__ acc, float* __restrict__ out) {
  if (threadIdx.x == 0 && blockIdx.x == 0) {
    float la = acc[0] / (float)((long)BB * L1);
    float lc = acc[1] / (float)(BB * CROP);
    out[0] = la + lc;
    out[1] = la;
    out[2] = lc;
  }
}

// ---- launch -----------------------------------------------------------------

extern "C" void kernel_launch(void* const* d_in, const int* in_sizes, int n_in,
                              void* d_out, int out_size, void* d_ws, size_t ws_size,
                              hipStream_t stream) {
  (void)in_sizes; (void)n_in; (void)out_size;
  const float* pred   = (const float*)d_in[0];
  const float* truea  = (const float*)d_in[1];
  const float* egf    = (const float*)d_in[2];
  const float* target = (const float*)d_in[3];
  float* out = (float*)d_out;

  char* ws = (char*)d_ws;
  const size_t off_best = (size_t)BB * CROW * 4;          // 29,368,320
  const size_t off_acc  = off_best + (size_t)BB * 8;
  const size_t off_tw   = off_acc + 256;
  const size_t off_w32  = off_tw + (size_t)FM * 8;
  const size_t off_spec = off_w32 + (size_t)8192 * 8;
  const size_t needed   = off_spec + (size_t)256 * FM * 8; // ~63.1 MB

  float* convbuf            = (float*)ws;
  unsigned long long* best  = (unsigned long long*)(ws + off_best);
  float* acc                = (float*)(ws + off_acc);
  float2* tw                = (float2*)(ws + off_tw);
  float2* w32               = (float2*)(ws + off_w32);
  float4* spec              = (float4*)(ws + off_spec);

  init_kernel<<<2, 256, 0, stream>>>(best, acc);

  if (ws_size >= needed) {
    twid_kernel<<<64, 256, 0, stream>>>(tw, w32);
    pipefft_kernel<<<BB / 2, 512, 0, stream>>>(pred, truea, egf, target, tw, w32,
                                               convbuf, spec, best, acc);
  } else {
    astf_kernel<<<1024, 256, 0, stream>>>(pred, truea, acc);
    conv_kernel<<<dim3(8, BB), 256, 0, stream>>>(pred, egf, convbuf);
    cc_kernel<<<dim3(15, BB), 256, 0, stream>>>(convbuf, target, best);
  }

  closs_kernel<<<dim3(BB), 256, 0, stream>>>(convbuf, target, best, acc);
  fin_kernel<<<1, 64, 0, stream>>>(acc, out);
}

// Round 12
// 246.185 us; speedup vs baseline: 1.0252x; 1.0252x over previous
//
#include <hip/hip_runtime.h>

// Problem constants
#define BB     512
#define L1     16384
#define L2     2048
#define CL     14337      // conv_len = L1 - L2 + 1
#define NCC    28673      // 2*CL - 1 (number of cc lags)
#define PADL   14336      // CL - 1
#define CROW   14340      // padded conv row stride (floats, %4==0)
#define CROP   256
#define CSTART 7040       // (CL - CROP)/2
#define TLEN   14337      // target row length
#define FM     16384      // complex FFT size
#define LOGM   14

// Padded LDS indexing: phys = i + (i>>4).
#define NPAD  17408       // 16384 + 16384/16
#define IDX(i) ((i) + ((i) >> 4))
// For digit-aligned offsets (base%16 + off%16 <= 15): IDX(base+off) ==
// IDX(base) + PADOFF(off) exactly, with PADOFF compile-time (verified per-S).
#define PADOFF(o) ((o) + ((o) >> 4))

// base-4 digit reversal of a 14-bit index (7 digits)
__device__ __forceinline__ int rev4_14(int x) {
  int b = (int)(__brev((unsigned)x) >> 18);
  return ((b & 0x1555) << 1) | ((b >> 1) & 0x1555);
}

__device__ __forceinline__ unsigned int fkey(float f) {
  unsigned int b = __float_as_uint(f);
  return b ^ ((b & 0x80000000u) ? 0xFFFFFFFFu : 0x80000000u);  // order-preserving
}

__device__ __forceinline__ float blockReduceSum256(float v) {
  #pragma unroll
  for (int o = 32; o > 0; o >>= 1) v += __shfl_down(v, o, 64);
  __shared__ float sws[4];
  if ((threadIdx.x & 63) == 0) sws[threadIdx.x >> 6] = v;
  __syncthreads();
  float r = 0.f;
  if (threadIdx.x == 0) r = sws[0] + sws[1] + sws[2] + sws[3];
  return r;
}

// ---------------- complex helpers -------------------------------------------
__device__ __forceinline__ float2 cmul(const float2 w, const float2 u) {
  return make_float2(w.x * u.x - w.y * u.y, w.x * u.y + w.y * u.x);
}
__device__ __forceinline__ float2 cmulc(const float2 x, const float2 w) {  // x*conj(w)
  return make_float2(w.x * x.x + w.y * x.y, w.x * x.y - w.y * x.x);
}

__device__ __forceinline__ void bf4_dif(float2& x0, float2& x1, float2& x2, float2& x3) {
  float t0r = x0.x + x2.x, t0i = x0.y + x2.y;
  float t1r = x1.x + x3.x, t1i = x1.y + x3.y;
  float t2r = x0.x - x2.x, t2i = x0.y - x2.y;
  float t3r = x1.y - x3.y, t3i = x3.x - x1.x;   // -i*(x1-x3)
  x0 = make_float2(t0r + t1r, t0i + t1i);
  x1 = make_float2(t2r + t3r, t2i + t3i);
  x2 = make_float2(t0r - t1r, t0i - t1i);
  x3 = make_float2(t2r - t3r, t2i - t3i);
}

__device__ __forceinline__ void bf4_dit(float2& x0, float2& x1, float2& x2, float2& x3) {
  float s0r = x0.x + x2.x, s0i = x0.y + x2.y;
  float s1r = x0.x - x2.x, s1i = x0.y - x2.y;
  float s2r = x1.x + x3.x, s2i = x1.y + x3.y;
  float s3r = x3.y - x1.y, s3i = x1.x - x3.x;   // i*(x1-x3)
  x0 = make_float2(s0r + s2r, s0i + s2i);
  x1 = make_float2(s1r + s3r, s1i + s3i);
  x2 = make_float2(s0r - s2r, s0i - s2i);
  x3 = make_float2(s1r - s3r, s1i - s3i);
}

// ---------------- radix-16 phase FFT cores (512 threads, padded LDS) ---------
// R7 structure (proven: 128 VGPR) + PADOFF base+immediate addressing.
// 1024-thread variants are dead: compiler pins VGPR=64 and spills (R5/R6/R8).
template <int S>
__device__ __forceinline__ void fft_dif4_pair(float2* A, const float2* __restrict__ tw,
                                              int tid) {
  __syncthreads();
  constexpr int Q  = 1 << (2 * S - 2);
  constexpr int TS = 12 - 2 * S;
  #pragma unroll 1
  for (int r = 0; r < 2; ++r) {
    const int bf = (r << 9) | tid;
    const int jq = bf & (Q - 1);
    const int hi = bf >> (2 * S - 2);
    const int pb = IDX((hi << (2 * S + 2)) | jq);
    float2 x[4][4];   // x[a][b] at base + a*4^S + b*4^(S-1)
    #pragma unroll
    for (int a = 0; a < 4; ++a)
      #pragma unroll
      for (int b = 0; b < 4; ++b)
        x[a][b] = A[pb + PADOFF((a << (2 * S)) + (b << (2 * S - 2)))];
    // stage S over a (twiddle j = b*Q + jq)
    #pragma unroll
    for (int b = 0; b < 4; ++b) {
      bf4_dif(x[0][b], x[1][b], x[2][b], x[3][b]);
      const int jt = (b * Q + jq) << TS;
      x[1][b] = cmul(tw[jt],     x[1][b]);
      x[2][b] = cmul(tw[2 * jt], x[2][b]);
      x[3][b] = cmul(tw[3 * jt], x[3][b]);
    }
    // stage S-1 over b (twiddle j2 = jq, shared across a)
    const int jt2 = jq << (14 - 2 * S);
    const float2 v1 = tw[jt2], v2 = tw[2 * jt2], v3 = tw[3 * jt2];
    #pragma unroll
    for (int a = 0; a < 4; ++a) {
      bf4_dif(x[a][0], x[a][1], x[a][2], x[a][3]);
      x[a][1] = cmul(v1, x[a][1]);
      x[a][2] = cmul(v2, x[a][2]);
      x[a][3] = cmul(v3, x[a][3]);
    }
    #pragma unroll
    for (int a = 0; a < 4; ++a)
      #pragma unroll
      for (int b = 0; b < 4; ++b)
        A[pb + PADOFF((a << (2 * S)) + (b << (2 * S - 2)))] = x[a][b];
  }
}

// Final DIF stage s=0 (twiddles == 1). i0%16 in {0,4,8,12} -> IDX(i0)+j exact.
__device__ __forceinline__ void fft_dif4_last(float2* A, int tid) {
  __syncthreads();
  for (int r = 0; r < 8; ++r) {
    const int p0 = IDX((((r << 9) | tid) << 2));
    float2 x0 = A[p0], x1 = A[p0 + 1], x2 = A[p0 + 2], x3 = A[p0 + 3];
    bf4_dif(x0, x1, x2, x3);
    A[p0] = x0; A[p0 + 1] = x1; A[p0 + 2] = x2; A[p0 + 3] = x3;
  }
}

// First DIT stage s=0 (twiddles == 1)
__device__ __forceinline__ void fft_dit4_first(float2* A, int tid) {
  __syncthreads();
  for (int r = 0; r < 8; ++r) {
    const int p0 = IDX((((r << 9) | tid) << 2));
    float2 x0 = A[p0], x1 = A[p0 + 1], x2 = A[p0 + 2], x3 = A[p0 + 3];
    bf4_dit(x0, x1, x2, x3);
    A[p0] = x0; A[p0 + 1] = x1; A[p0 + 2] = x2; A[p0 + 3] = x3;
  }
}

// Merged DIT stage pair (S, S+1), S in {1,3,5}
template <int S>
__device__ __forceinline__ void fft_dit4_pair(float2* A, const float2* __restrict__ tw,
                                              int tid) {
  __syncthreads();
  constexpr int M = 1 << (2 * S);
  #pragma unroll 1
  for (int r = 0; r < 2; ++r) {
    const int bf = (r << 9) | tid;
    const int jq = bf & (M - 1);
    const int hi = bf >> (2 * S);
    const int pb = IDX((hi << (2 * S + 4)) | jq);
    float2 x[4][4];   // x[a][b] at base + b*4M + a*M
    #pragma unroll
    for (int a = 0; a < 4; ++a)
      #pragma unroll
      for (int b = 0; b < 4; ++b)
        x[a][b] = A[pb + PADOFF((b << (2 * S + 2)) + (a << (2 * S)))];
    // stage S over a: j = jq (same twiddles for all b)
    const int jt = jq << (12 - 2 * S);
    const float2 w1 = tw[jt], w2 = tw[2 * jt], w3 = tw[3 * jt];
    #pragma unroll
    for (int b = 0; b < 4; ++b) {
      x[1][b] = cmulc(x[1][b], w1);
      x[2][b] = cmulc(x[2][b], w2);
      x[3][b] = cmulc(x[3][b], w3);
      bf4_dit(x[0][b], x[1][b], x[2][b], x[3][b]);
    }
    // stage S+1 over b: j' = a*M + jq
    #pragma unroll
    for (int a = 0; a < 4; ++a) {
      const int jt2 = (a * M + jq) << (10 - 2 * S);
      x[a][1] = cmulc(x[a][1], tw[jt2]);
      x[a][2] = cmulc(x[a][2], tw[2 * jt2]);
      x[a][3] = cmulc(x[a][3], tw[3 * jt2]);
      bf4_dit(x[a][0], x[a][1], x[a][2], x[a][3]);
    }
    #pragma unroll
    for (int a = 0; a < 4; ++a)
      #pragma unroll
      for (int b = 0; b < 4; ++b)
        A[pb + PADOFF((b << (2 * S + 2)) + (a << (2 * S)))] = x[a][b];
  }
}

// DIF forward: natural-order input -> base-4 digit-reversed output (Y[k] at rev4_14(k))
__device__ __forceinline__ void fft_dif4(float2* A, const float2* __restrict__ tw, int tid) {
  fft_dif4_pair<6>(A, tw, tid);
  fft_dif4_pair<4>(A, tw, tid);
  fft_dif4_pair<2>(A, tw, tid);
  fft_dif4_last(A, tid);
  __syncthreads();
}

// DIT inverse (conjugate twiddles, unnormalized): digit-reversed input -> natural output
__device__ __forceinline__ void fft_dit4_inv(float2* A, const float2* __restrict__ tw, int tid) {
  fft_dit4_first(A, tid);
  fft_dit4_pair<1>(A, tw, tid);
  fft_dit4_pair<3>(A, tw, tid);
  fft_dit4_pair<5>(A, tw, tid);
  __syncthreads();
}

// ---- common small kernels ---------------------------------------------------

__global__ void init_kernel(unsigned long long* best, float* acc) {
  int i = blockIdx.x * blockDim.x + threadIdx.x;
  if (i < BB) best[i] = 0ull;
  if (i < 4)  acc[i]  = 0.f;
}

__global__ void twid_kernel(float2* tw, float2* w32) {
  int i = blockIdx.x * 256 + threadIdx.x;
  if (i < FM) {
    double a = -2.0 * 3.14159265358979323846 * (double)i / (double)FM;
    tw[i] = make_float2((float)cos(a), (float)sin(a));
  }
  if (i < 8192) {
    double a = -2.0 * 3.14159265358979323846 * (double)i / (double)(2 * FM);
    w32[i] = make_float2((float)cos(a), (float)sin(a));
  }
}

__global__ void astf_kernel(const float* __restrict__ p, const float* __restrict__ t,
                            float* __restrict__ acc) {
  int gid = blockIdx.x * blockDim.x + threadIdx.x;
  int stride = gridDim.x * blockDim.x;
  const float4* p4 = (const float4*)p;
  const float4* t4 = (const float4*)t;
  const int n4 = (BB * L1) / 4;
  float s = 0.f;
  for (int i = gid; i < n4; i += stride) {
    float4 a = p4[i], b = t4[i];
    float dx = a.x - b.x, dy = a.y - b.y, dz = a.z - b.z, dw = a.w - b.w;
    s += dx * dx + dy * dy + dz * dz + dw * dw;
  }
  s = blockReduceSum256(s);
  if (threadIdx.x == 0) atomicAdd(&acc[0], s);
}

// ---- FUSED FFT pipeline: astf-MSE + conv (circ corr @16384) + cc (rfft-32768)
// One block handles 2 batches end-to-end. R12 fix: the conv->packed repack
// stages only the LOWER quarter (i<4096) in registers (8 float2 = 16 VGPR;
// R11's 15 float2 = 30 VGPR spilled ~31 MB/dispatch to scratch). The
// i in [4096,8192) chunk reads A-positions [8192,14338) which are DISJOINT
// from all repack writes ([0,8192)) -> direct LDS->LDS copy, no staging.
// Upper-half zeroing happens after a barrier that closes those reads.
__global__ __launch_bounds__(512, 2) void pipefft_kernel(const float* __restrict__ pred,
                                                         const float* __restrict__ truea,
                                                         const float* __restrict__ egf,
                                                         const float* __restrict__ target,
                                                         const float2* __restrict__ tw,
                                                         const float2* __restrict__ w32,
                                                         float* convbuf,
                                                         float4* __restrict__ spec,
                                                         unsigned long long* __restrict__ best,
                                                         float* __restrict__ acc) {
  __shared__ float2 A[NPAD];
  __shared__ unsigned long long sbest[8];
  __shared__ float swsum[8];
  const int tid = threadIdx.x;
  float4* sp = spec + (size_t)blockIdx.x * 8192;
  float asum = 0.f;

  for (int half = 0; half < 2; ++half) {
    const int b = blockIdx.x * 2 + half;
    const float* pb = pred  + (size_t)b * L1;
    const float* tb = truea + (size_t)b * L1;
    const float* eb = egf   + (size_t)b * L2;
    float* cr       = convbuf + (size_t)b * CROW;
    const float* tr = target  + (size_t)b * TLEN;

    // ===== conv pack (+ fused astf MSE): z = pred + i*egf ====================
    for (int i = tid; i < FM; i += 512) {
      float pv = pb[i];
      float d  = pv - tb[i];
      asum += d * d;
      A[IDX(i)] = make_float2(pv, (i < L2) ? eb[i] : 0.f);
    }

    fft_dif4(A, tw, tid);

    for (int rr = 0; rr < 16; ++rr) {
      const int k = tid * 16 + rr;
      if (k == 0) {
        float2 z0 = A[IDX(0)];
        A[IDX(0)] = make_float2(z0.x * z0.y, 0.f);
        const int p = IDX(2);                 // rev4(8192) == 2
        float2 zn = A[p];
        A[p] = make_float2(zn.x * zn.y, 0.f);
      } else {
        const int p = IDX(rev4_14(k)), q = IDX(rev4_14(FM - k));
        float2 z1 = A[p], z2 = A[q];
        float pr = 0.5f * (z1.x + z2.x), pi = 0.5f * (z1.y - z2.y);   // PRED[k]
        float er = 0.5f * (z1.y + z2.y), ei = 0.5f * (z2.x - z1.x);   // EGF[k]
        float sr = pr * er + pi * ei;                                  // S = PRED*conj(EGF)
        float si = pi * er - pr * ei;
        A[p] = make_float2(sr, si);
        A[q] = make_float2(sr, -si);
      }
    }

    fft_dit4_inv(A, tw, tid);   // A[IDX(n)].x = conv[n]*FM, natural order

    // ===== low-register repack: store conv row + build x[i]=(c[2i],c[2i+1]) ==
    const float sc = 1.f / (float)FM;
    // chunk B (i < 4096): reads [0,8192) overlap writes -> stage 8 float2
    float2 v[8];
    #pragma unroll
    for (int r = 0; r < 8; ++r) {
      const int i = tid + (r << 9);           // i in [0,4096)
      const int p = IDX(2 * i);               // 2i%16 <= 14 -> adjacent pair
      float c0 = A[p].x * sc, c1 = A[p + 1].x * sc;
      *(float2*)(cr + 2 * i) = make_float2(c0, c1);
      v[r] = make_float2(c0, c1);
    }
    __syncthreads();   // all chunk-B reads complete before any repack write

    // chunk A (i in [4096,8192)): reads [8192,14338) disjoint from writes [0,8192)
    #pragma unroll 1
    for (int r = 8; r < 16; ++r) {
      const int i = tid + (r << 9);
      float c0 = 0.f, c1 = 0.f;
      if (i < 7168) {                         // 2i+1 <= 14335 < CL
        const int p = IDX(2 * i);
        c0 = A[p].x * sc; c1 = A[p + 1].x * sc;
        *(float2*)(cr + 2 * i) = make_float2(c0, c1);
      } else if (i == 7168) {
        c0 = A[IDX(14336)].x * sc;            // 14336 == CL-1
        cr[14336] = c0;
      }
      A[IDX(i)] = make_float2(c0, c1);
    }
    // chunk B write from registers (writes [0,4096), disjoint from chunk-A reads)
    #pragma unroll
    for (int r = 0; r < 8; ++r) {
      const int i = tid + (r << 9);
      A[IDX(i)] = v[r];
    }
    __syncthreads();   // close chunk-A reads of [8192,14338) before zeroing

    for (int i = tid + 8192; i < FM; i += 512)
      A[IDX(i)] = make_float2(0.f, 0.f);
    // fft_dif4 opens with __syncthreads -> zeros visible

    fft_dif4(A, tw, tid);                     // Yc of packed conv

    // stash Yc in glue order (coalesced float4): sp[(rr<<9)|tid] =
    // (Yc[rev4(k)], Yc[rev4(FM-k)]) for k = tid*16+rr; (0,8192) in k==0 slot
    #pragma unroll 1
    for (int rr = 0; rr < 16; ++rr) {
      const int k = tid * 16 + rr;
      const int s = (rr << 9) | tid;
      float2 ya, yb;
      if (k == 0) { ya = A[IDX(0)]; yb = A[IDX(2)]; }   // rev4(8192) == 2
      else        { ya = A[IDX(rev4_14(k))]; yb = A[IDX(rev4_14(FM - k))]; }
      sp[s] = make_float4(ya.x, ya.y, yb.x, yb.y);
    }
    __syncthreads();

    // target packed even/odd (TLEN odd -> rows misaligned for odd b; scalar)
    for (int i = tid; i < FM; i += 512) {
      int g = 2 * i;
      float re = (g     < TLEN) ? tr[g]     : 0.f;
      float im = (g + 1 < TLEN) ? tr[g + 1] : 0.f;
      A[IDX(i)] = make_float2(re, im);
    }
    fft_dif4(A, tw, tid);                                    // A = Yt

    // glue: build y' spectrum of the packed cc sequence, in digit-rev slots
    #pragma unroll 1
    for (int rr = 0; rr < 16; ++rr) {
      const int k = tid * 16 + rr;
      const int s = (rr << 9) | tid;
      const float4 y4 = sp[s];                        // coalesced
      if (k == 0) {
        float2 yc0 = make_float2(y4.x, y4.y), yt0 = A[IDX(0)];
        float X0 = yc0.x + yc0.y, XM = yc0.x - yc0.y;
        float T0 = yt0.x + yt0.y, TM = yt0.x - yt0.y;
        float C0 = X0 * T0, CM = XM * TM;
        A[IDX(0)] = make_float2(0.5f * (C0 + CM), 0.5f * (C0 - CM));
        // bin 8192 (self-paired): rev4(8192) == 2
        float2 yc = make_float2(y4.z, y4.w), yt = A[IDX(2)];
        float cr8 = yc.x * yt.x + yc.y * yt.y;
        float ci8 = yc.x * yt.y - yc.y * yt.x;
        A[IDX(2)] = make_float2(cr8, -ci8);
      } else {
        const int p = IDX(rev4_14(k)), q = IDX(rev4_14(FM - k));
        const float2 w = w32[k];                        // e^{-2*pi*i*k/32768}
        // X[k], X[M-k] from Yc (coalesced stash)
        float2 ya = make_float2(y4.x, y4.y), yb = make_float2(y4.z, y4.w);
        float xer = 0.5f * (ya.x + yb.x), xei = 0.5f * (ya.y - yb.y);
        float dr  = 0.5f * (ya.x - yb.x), di  = 0.5f * (ya.y + yb.y);
        float xo_r = di, xo_i = -dr;                    // Xo = -i*D
        float wxr = w.x * xo_r - w.y * xo_i, wxi = w.x * xo_i + w.y * xo_r;
        float Xkr = xer + wxr, Xki = xei + wxi;
        float Xmr = xer - wxr, Xmi = -(xei - wxi);      // X[M-k] = conj(Xe - W*Xo)
        // T[k], T[M-k] from Yt
        float2 ta = A[p], tb2 = A[q];
        float ter = 0.5f * (ta.x + tb2.x), tei = 0.5f * (ta.y - tb2.y);
        float er2 = 0.5f * (ta.x - tb2.x), ei2 = 0.5f * (ta.y + tb2.y);
        float to_r = ei2, to_i = -er2;
        float twr = w.x * to_r - w.y * to_i, twi = w.x * to_i + w.y * to_r;
        float Tkr = ter + twr, Tki = tei + twi;
        float Tmr = ter - twr, Tmi = -(tei - twi);
        // C[k]=X[k]*conj(T[k]); C[M-k]=X[M-k]*conj(T[M-k])
        float Ckr = Xkr * Tkr + Xki * Tki, Cki = Xki * Tkr - Xkr * Tki;
        float Cmr = Xmr * Tmr + Xmi * Tmi, Cmi = Xmi * Tmr - Xmr * Tmi;
        // y'[k] = Ce + i*V*D, V = conj(w)
        float aer = 0.5f * (Ckr + Cmr), aei = 0.5f * (Cki - Cmi);
        float bdr = 0.5f * (Ckr - Cmr), bdi = 0.5f * (Cki + Cmi);
        float cor_ = w.x * bdr + w.y * bdi, coi = w.x * bdi - w.y * bdr;
        A[p] = make_float2(aer - coi, aei + cor_);
        // y'[M-k] = Ce2 + i*(-w)*D2
        float a2r = 0.5f * (Cmr + Ckr), a2i = 0.5f * (Cmi - Cki);
        float d2r = 0.5f * (Cmr - Ckr), d2i = 0.5f * (Cmi + Cki);
        float c2r = -(w.x * d2r - w.y * d2i), c2i = -(w.x * d2i + w.y * d2r);
        A[q] = make_float2(a2r - c2i, a2i + c2r);
      }
    }

    fft_dit4_inv(A, tw, tid);  // A[n] = (cc[2n], cc[2n+1]) * FM

    // argmax with j->np mapping: j<=14336 -> np=j ; (14336,18432) dead ; j>=18432 -> np=j-4095
    unsigned long long pk = 0ull;
    for (int i = tid; i < FM; i += 512) {
      float2 v2 = A[IDX(i)];
      int j0 = 2 * i, j1 = 2 * i + 1;
      if (j0 <= 14336) {
        unsigned long long p = ((unsigned long long)fkey(v2.x) << 32)
                             | (unsigned long long)(0xFFFFFFFFu - (unsigned)j0);
        if (p > pk) pk = p;
      } else if (j0 >= 18432) {
        unsigned long long p = ((unsigned long long)fkey(v2.x) << 32)
                             | (unsigned long long)(0xFFFFFFFFu - (unsigned)(j0 - 4095));
        if (p > pk) pk = p;
      }
      if (j1 <= 14336) {
        unsigned long long p = ((unsigned long long)fkey(v2.y) << 32)
                             | (unsigned long long)(0xFFFFFFFFu - (unsigned)j1);
        if (p > pk) pk = p;
      } else if (j1 >= 18432) {
        unsigned long long p = ((unsigned long long)fkey(v2.y) << 32)
                             | (unsigned long long)(0xFFFFFFFFu - (unsigned)(j1 - 4095));
        if (p > pk) pk = p;
      }
    }
    #pragma unroll
    for (int o = 32; o > 0; o >>= 1) {
      unsigned long long q = __shfl_down(pk, o, 64);
      if (q > pk) pk = q;
    }
    if ((tid & 63) == 0) sbest[tid >> 6] = pk;
    __syncthreads();
    if (tid == 0) {
      #pragma unroll
      for (int i = 1; i < 8; ++i) if (sbest[i] > pk) pk = sbest[i];
      best[b] = pk;
    }
    __syncthreads();
  }

  // ===== fused astf MSE reduction (both halves), one atomic per block ========
  #pragma unroll
  for (int o = 32; o > 0; o >>= 1) asum += __shfl_down(asum, o, 64);
  if ((tid & 63) == 0) swsum[tid >> 6] = asum;
  __syncthreads();
  if (tid == 0) {
    float s = 0.f;
    #pragma unroll
    for (int i = 0; i < 8; ++i) s += swsum[i];
    atomicAdd(&acc[0], s);
  }
}

// ---- fallback direct path (proven r3 kernels) -------------------------------

__device__ __forceinline__ void taps4(float* acc, const float4 a, const float4 b,
                                      const float4 e) {
  acc[0] = fmaf(a.x, e.x, acc[0]); acc[0] = fmaf(a.y, e.y, acc[0]);
  acc[0] = fmaf(a.z, e.z, acc[0]); acc[0] = fmaf(a.w, e.w, acc[0]);
  acc[1] = fmaf(a.y, e.x, acc[1]); acc[1] = fmaf(a.z, e.y, acc[1]);
  acc[1] = fmaf(a.w, e.z, acc[1]); acc[1] = fmaf(b.x, e.w, acc[1]);
  acc[2] = fmaf(a.z, e.x, acc[2]); acc[2] = fmaf(a.w, e.y, acc[2]);
  acc[2] = fmaf(b.x, e.z, acc[2]); acc[2] = fmaf(b.y, e.w, acc[2]);
  acc[3] = fmaf(a.w, e.x, acc[3]); acc[3] = fmaf(b.x, e.y, acc[3]);
  acc[3] = fmaf(b.y, e.z, acc[3]); acc[3] = fmaf(b.z, e.w, acc[3]);
}

__device__ __forceinline__ float4 gload4(const float* __restrict__ cr, int g) {
  if (g >= 0 && g + 3 < CL) return *(const float4*)(cr + g);
  float4 v;
  int g0 = min(max(g,     0), CL - 1);
  int g1 = min(max(g + 1, 0), CL - 1);
  int g2 = min(max(g + 2, 0), CL - 1);
  int g3 = min(max(g + 3, 0), CL - 1);
  v.x = (g     >= 0 && g     < CL) ? cr[g0] : 0.f;
  v.y = (g + 1 >= 0 && g + 1 < CL) ? cr[g1] : 0.f;
  v.z = (g + 2 >= 0 && g + 2 < CL) ? cr[g2] : 0.f;
  v.w = (g + 3 >= 0 && g + 3 < CL) ? cr[g3] : 0.f;
  return v;
}

__global__ __launch_bounds__(256) void conv_kernel(const float* __restrict__ pred,
                                                   const float* __restrict__ egf,
                                                   float* __restrict__ convbuf) {
  const int b = blockIdx.y;
  const int x = blockIdx.x;
  const int tid = threadIdx.x;
  const float* pb = pred + (size_t)b * L1;
  const float* eg = egf  + (size_t)b * L2;
  float* cr = convbuf + (size_t)b * CROW;

  if (x == 7) {
    float s = 0.f;
    const int k0 = tid * 8;
    #pragma unroll
    for (int j = 0; j < 8; ++j) s += pb[PADL + k0 + j] * eg[k0 + j];
    s = blockReduceSum256(s);
    if (tid == 0) cr[PADL] = s;
    return;
  }

  const int m = x * 2048 + tid * 8;
  const float* cp = pb + m;
  float accA[4] = {0.f,0.f,0.f,0.f};
  float accB[4] = {0.f,0.f,0.f,0.f};
  float4 w0 = *(const float4*)(cp);
  float4 w1 = *(const float4*)(cp + 4);
  float4 w2 = *(const float4*)(cp + 8);

  #pragma unroll 4
  for (int k = 0; k < L2 - 4; k += 4) {
    const float4 e  = *(const float4*)(eg + k);
    const float4 nx = *(const float4*)(cp + k + 12);
    taps4(accA, w0, w1, e);
    taps4(accB, w1, w2, e);
    w0 = w1; w1 = w2; w2 = nx;
  }
  {
    const float4 e = *(const float4*)(eg + (L2 - 4));
    taps4(accA, w0, w1, e);
    taps4(accB, w1, w2, e);
  }

  *(float4*)(cr + m)     = make_float4(accA[0], accA[1], accA[2], accA[3]);
  *(float4*)(cr + m + 4) = make_float4(accB[0], accB[1], accB[2], accB[3]);
}

__global__ __launch_bounds__(256) void cc_kernel(const float* __restrict__ convbuf,
                                                 const float* __restrict__ target,
                                                 unsigned long long* __restrict__ best) {
  __shared__ unsigned long long sbest[4];
  const int b   = blockIdx.y;
  const int m0  = blockIdx.x * 2048;
  const int tid = threadIdx.x;
  const float* cr = convbuf + (size_t)b * CROW;
  const float* tr = target  + (size_t)b * TLEN;
  const int m    = m0 + tid * 8;
  const int gofs = m - PADL;

  float accA[4] = {0.f,0.f,0.f,0.f};
  float accB[4] = {0.f,0.f,0.f,0.f};

  const int t1raw = PADL - m0;
  const int t1    = t1raw > 0 ? t1raw : 0;
  const int t2    = PADL + CL - m0 - 2047;
  int tIntHi      = (t2 - 16) & ~3;
  if (tIntHi > 14332) tIntHi = 14332;
  if (tIntHi < t1)    tIntHi = t1;
  int e0 = (t1raw - 2047) > 0 ? ((t1raw - 2047) & ~3) : 0;
  const int eH = min(TLEN, NCC - m0);

  if (e0 < t1) {
    float4 w0 = gload4(cr, gofs + e0);
    float4 w1 = gload4(cr, gofs + e0 + 4);
    float4 w2 = gload4(cr, gofs + e0 + 8);
    #pragma unroll 2
    for (int t = e0; t < t1; t += 4) {
      const float4 e  = *(const float4*)(tr + t);
      const float4 nx = gload4(cr, gofs + t + 12);
      taps4(accA, w0, w1, e);
      taps4(accB, w1, w2, e);
      w0 = w1; w1 = w2; w2 = nx;
    }
  }

  if (t1 < tIntHi) {
    const float* cp = cr + gofs;
    float4 w0 = *(const float4*)(cp + t1);
    float4 w1 = *(const float4*)(cp + t1 + 4);
    float4 w2 = *(const float4*)(cp + t1 + 8);
    #pragma unroll 4
    for (int t = t1; t < tIntHi; t += 4) {
      const float4 e  = *(const float4*)(tr + t);
      const float4 nx = *(const float4*)(cp + t + 12);
      taps4(accA, w0, w1, e);
      taps4(accB, w1, w2, e);
      w0 = w1; w1 = w2; w2 = nx;
    }
  }

  if (tIntHi < eH) {
    float4 w0 = gload4(cr, gofs + tIntHi);
    float4 w1 = gload4(cr, gofs + tIntHi + 4);
    float4 w2 = gload4(cr, gofs + tIntHi + 8);
    #pragma unroll 2
    for (int t = tIntHi; t < eH; t += 4) {
      float4 e;
      e.x = (t     < TLEN) ? tr[t]     : 0.f;
      e.y = (t + 1 < TLEN) ? tr[t + 1] : 0.f;
      e.z = (t + 2 < TLEN) ? tr[t + 2] : 0.f;
      e.w = (t + 3 < TLEN) ? tr[t + 3] : 0.f;
      const float4 nx = gload4(cr, gofs + t + 12);
      taps4(accA, w0, w1, e);
      taps4(accB, w1, w2, e);
      w0 = w1; w1 = w2; w2 = nx;
    }
  }

  unsigned long long pk = 0ull;
  #pragma unroll
  for (int j = 0; j < 4; ++j) {
    int mm = m + j;
    if (mm < NCC) {
      int np = (mm >= PADL) ? (mm - PADL) : (mm + CL);
      unsigned long long p = ((unsigned long long)fkey(accA[j]) << 32)
                           | (unsigned long long)(0xFFFFFFFFu - (unsigned)np);
      if (p > pk) pk = p;
    }
    mm = m + 4 + j;
    if (mm < NCC) {
      int np = (mm >= PADL) ? (mm - PADL) : (mm + CL);
      unsigned long long p = ((unsigned long long)fkey(accB[j]) << 32)
                           | (unsigned long long)(0xFFFFFFFFu - (unsigned)np);
      if (p > pk) pk = p;
    }
  }
  #pragma unroll
  for (int o = 32; o > 0; o >>= 1) {
    unsigned long long q = __shfl_down(pk, o, 64);
    if (q > pk) pk = q;
  }
  if ((tid & 63) == 0) sbest[tid >> 6] = pk;
  __syncthreads();
  if (tid == 0) {
    #pragma unroll
    for (int i = 1; i < 4; ++i) if (sbest[i] > pk) pk = sbest[i];
    atomicMax(best + b, pk);
  }
}

__global__ void closs_kernel(const float* __restrict__ convbuf,
                             const float* __restrict__ target,
                             const unsigned long long* __restrict__ best,
                             float* __restrict__ acc) {
  const int b = blockIdx.x;
  const int np = (int)(0xFFFFFFFFu - (unsigned)(best[b] & 0xFFFFFFFFull));
  const int shift = np - PADL;
  const int jj = CSTART + threadIdx.x;
  int pos = jj + shift;
  if (pos < 0) pos += CL; else if (pos >= CL) pos -= CL;
  float d = convbuf[(size_t)b * CROW + pos] - target[(size_t)b * TLEN + jj];
  float s = blockReduceSum256(d * d);
  if (threadIdx.x == 0) atomicAdd(&acc[1], s);
}

__global__ void fin_kernel(const float* __restrict__ acc, float* __restrict__ out) {
  if (threadIdx.x == 0 && blockIdx.x == 0) {
    float la = acc[0] / (float)((long)BB * L1);
    float lc = acc[1] / (float)(BB * CROP);
    out[0] = la + lc;
    out[1] = la;
    out[2] = lc;
  }
}

// ---- launch -----------------------------------------------------------------

extern "C" void kernel_launch(void* const* d_in, const int* in_sizes, int n_in,
                              void* d_out, int out_size, void* d_ws, size_t ws_size,
                              hipStream_t stream) {
  (void)in_sizes; (void)n_in; (void)out_size;
  const float* pred   = (const float*)d_in[0];
  const float* truea  = (const float*)d_in[1];
  const float* egf    = (const float*)d_in[2];
  const float* target = (const float*)d_in[3];
  float* out = (float*)d_out;

  char* ws = (char*)d_ws;
  const size_t off_best = (size_t)BB * CROW * 4;          // 29,368,320
  const size_t off_acc  = off_best + (size_t)BB * 8;
  const size_t off_tw   = off_acc + 256;
  const size_t off_w32  = off_tw + (size_t)FM * 8;
  const size_t off_spec = off_w32 + (size_t)8192 * 8;
  const size_t needed   = off_spec + (size_t)256 * FM * 8; // ~63.1 MB

  float* convbuf            = (float*)ws;
  unsigned long long* best  = (unsigned long long*)(ws + off_best);
  float* acc                = (float*)(ws + off_acc);
  float2* tw                = (float2*)(ws + off_tw);
  float2* w32               = (float2*)(ws + off_w32);
  float4* spec              = (float4*)(ws + off_spec);

  init_kernel<<<2, 256, 0, stream>>>(best, acc);

  if (ws_size >= needed) {
    twid_kernel<<<64, 256, 0, stream>>>(tw, w32);
    pipefft_kernel<<<BB / 2, 512, 0, stream>>>(pred, truea, egf, target, tw, w32,
                                               convbuf, spec, best, acc);
  } else {
    astf_kernel<<<1024, 256, 0, stream>>>(pred, truea, acc);
    conv_kernel<<<dim3(8, BB), 256, 0, stream>>>(pred, egf, convbuf);
    cc_kernel<<<dim3(15, BB), 256, 0, stream>>>(convbuf, target, best);
  }

  closs_kernel<<<dim3(BB), 256, 0, stream>>>(convbuf, target, best, acc);
  fin_kernel<<<1, 64, 0, stream>>>(acc, out);
}

// Round 13
// 231.828 us; speedup vs baseline: 1.0887x; 1.0619x over previous
//
#include <hip/hip_runtime.h>

// Problem constants
#define BB     512
#define L1     16384
#define L2     2048
#define CL     14337      // conv_len = L1 - L2 + 1
#define NCC    28673      // 2*CL - 1 (number of cc lags)
#define PADL   14336      // CL - 1
#define CROW   14340      // padded conv row stride (floats, %4==0)
#define CROP   256
#define CSTART 7040       // (CL - CROP)/2
#define TLEN   14337      // target row length
#define FM     16384      // complex FFT size
#define LOGM   14

// Padded LDS indexing: phys = i + (i>>4).
#define NPAD  17408       // 16384 + 16384/16
#define IDX(i) ((i) + ((i) >> 4))
// For digit-aligned offsets (base%16 + off%16 <= 15): IDX(base+off) ==
// IDX(base) + PADOFF(off) exactly, with PADOFF compile-time (verified per-S).
#define PADOFF(o) ((o) + ((o) >> 4))

// base-4 digit reversal of a 14-bit index (7 digits)
__device__ __forceinline__ int rev4_14(int x) {
  int b = (int)(__brev((unsigned)x) >> 18);
  return ((b & 0x1555) << 1) | ((b >> 1) & 0x1555);
}

__device__ __forceinline__ unsigned int fkey(float f) {
  unsigned int b = __float_as_uint(f);
  return b ^ ((b & 0x80000000u) ? 0xFFFFFFFFu : 0x80000000u);  // order-preserving
}

__device__ __forceinline__ float blockReduceSum256(float v) {
  #pragma unroll
  for (int o = 32; o > 0; o >>= 1) v += __shfl_down(v, o, 64);
  __shared__ float sws[4];
  if ((threadIdx.x & 63) == 0) sws[threadIdx.x >> 6] = v;
  __syncthreads();
  float r = 0.f;
  if (threadIdx.x == 0) r = sws[0] + sws[1] + sws[2] + sws[3];
  return r;
}

// ---------------- complex helpers -------------------------------------------
__device__ __forceinline__ float2 cmul(const float2 w, const float2 u) {
  return make_float2(w.x * u.x - w.y * u.y, w.x * u.y + w.y * u.x);
}
__device__ __forceinline__ float2 cmulc(const float2 x, const float2 w) {  // x*conj(w)
  return make_float2(w.x * x.x + w.y * x.y, w.x * x.y - w.y * x.x);
}

__device__ __forceinline__ void bf4_dif(float2& x0, float2& x1, float2& x2, float2& x3) {
  float t0r = x0.x + x2.x, t0i = x0.y + x2.y;
  float t1r = x1.x + x3.x, t1i = x1.y + x3.y;
  float t2r = x0.x - x2.x, t2i = x0.y - x2.y;
  float t3r = x1.y - x3.y, t3i = x3.x - x1.x;   // -i*(x1-x3)
  x0 = make_float2(t0r + t1r, t0i + t1i);
  x1 = make_float2(t2r + t3r, t2i + t3i);
  x2 = make_float2(t0r - t1r, t0i - t1i);
  x3 = make_float2(t2r - t3r, t2i - t3i);
}

__device__ __forceinline__ void bf4_dit(float2& x0, float2& x1, float2& x2, float2& x3) {
  float s0r = x0.x + x2.x, s0i = x0.y + x2.y;
  float s1r = x0.x - x2.x, s1i = x0.y - x2.y;
  float s2r = x1.x + x3.x, s2i = x1.y + x3.y;
  float s3r = x3.y - x1.y, s3i = x1.x - x3.x;   // i*(x1-x3)
  x0 = make_float2(s0r + s2r, s0i + s2i);
  x1 = make_float2(s1r + s3r, s1i + s3i);
  x2 = make_float2(s0r - s2r, s0i - s2i);
  x3 = make_float2(s1r - s3r, s1i - s3i);
}

// ---------------- radix-16 phase FFT cores (512 threads, padded LDS) ---------
// R7 structure (proven: 128 VGPR) + PADOFF base+immediate addressing.
// 1024-thread variants are dead: compiler pins VGPR=64 and spills (R5/R6/R8).
// Register-staging data across barriers is also dead: even 16 VGPRs of stash
// spilled ~21 MB/dispatch (R11/R12) -> conv repack uses the L2-hot global
// round-trip (R10's proven pattern).
template <int S>
__device__ __forceinline__ void fft_dif4_pair(float2* A, const float2* __restrict__ tw,
                                              int tid) {
  __syncthreads();
  constexpr int Q  = 1 << (2 * S - 2);
  constexpr int TS = 12 - 2 * S;
  #pragma unroll 1
  for (int r = 0; r < 2; ++r) {
    const int bf = (r << 9) | tid;
    const int jq = bf & (Q - 1);
    const int hi = bf >> (2 * S - 2);
    const int pb = IDX((hi << (2 * S + 2)) | jq);
    float2 x[4][4];   // x[a][b] at base + a*4^S + b*4^(S-1)
    #pragma unroll
    for (int a = 0; a < 4; ++a)
      #pragma unroll
      for (int b = 0; b < 4; ++b)
        x[a][b] = A[pb + PADOFF((a << (2 * S)) + (b << (2 * S - 2)))];
    // stage S over a (twiddle j = b*Q + jq)
    #pragma unroll
    for (int b = 0; b < 4; ++b) {
      bf4_dif(x[0][b], x[1][b], x[2][b], x[3][b]);
      const int jt = (b * Q + jq) << TS;
      x[1][b] = cmul(tw[jt],     x[1][b]);
      x[2][b] = cmul(tw[2 * jt], x[2][b]);
      x[3][b] = cmul(tw[3 * jt], x[3][b]);
    }
    // stage S-1 over b (twiddle j2 = jq, shared across a)
    const int jt2 = jq << (14 - 2 * S);
    const float2 v1 = tw[jt2], v2 = tw[2 * jt2], v3 = tw[3 * jt2];
    #pragma unroll
    for (int a = 0; a < 4; ++a) {
      bf4_dif(x[a][0], x[a][1], x[a][2], x[a][3]);
      x[a][1] = cmul(v1, x[a][1]);
      x[a][2] = cmul(v2, x[a][2]);
      x[a][3] = cmul(v3, x[a][3]);
    }
    #pragma unroll
    for (int a = 0; a < 4; ++a)
      #pragma unroll
      for (int b = 0; b < 4; ++b)
        A[pb + PADOFF((a << (2 * S)) + (b << (2 * S - 2)))] = x[a][b];
  }
}

// Final DIF stage s=0 (twiddles == 1). i0%16 in {0,4,8,12} -> IDX(i0)+j exact.
__device__ __forceinline__ void fft_dif4_last(float2* A, int tid) {
  __syncthreads();
  for (int r = 0; r < 8; ++r) {
    const int p0 = IDX((((r << 9) | tid) << 2));
    float2 x0 = A[p0], x1 = A[p0 + 1], x2 = A[p0 + 2], x3 = A[p0 + 3];
    bf4_dif(x0, x1, x2, x3);
    A[p0] = x0; A[p0 + 1] = x1; A[p0 + 2] = x2; A[p0 + 3] = x3;
  }
}

// First DIT stage s=0 (twiddles == 1)
__device__ __forceinline__ void fft_dit4_first(float2* A, int tid) {
  __syncthreads();
  for (int r = 0; r < 8; ++r) {
    const int p0 = IDX((((r << 9) | tid) << 2));
    float2 x0 = A[p0], x1 = A[p0 + 1], x2 = A[p0 + 2], x3 = A[p0 + 3];
    bf4_dit(x0, x1, x2, x3);
    A[p0] = x0; A[p0 + 1] = x1; A[p0 + 2] = x2; A[p0 + 3] = x3;
  }
}

// Merged DIT stage pair (S, S+1), S in {1,3,5}
template <int S>
__device__ __forceinline__ void fft_dit4_pair(float2* A, const float2* __restrict__ tw,
                                              int tid) {
  __syncthreads();
  constexpr int M = 1 << (2 * S);
  #pragma unroll 1
  for (int r = 0; r < 2; ++r) {
    const int bf = (r << 9) | tid;
    const int jq = bf & (M - 1);
    const int hi = bf >> (2 * S);
    const int pb = IDX((hi << (2 * S + 4)) | jq);
    float2 x[4][4];   // x[a][b] at base + b*4M + a*M
    #pragma unroll
    for (int a = 0; a < 4; ++a)
      #pragma unroll
      for (int b = 0; b < 4; ++b)
        x[a][b] = A[pb + PADOFF((b << (2 * S + 2)) + (a << (2 * S)))];
    // stage S over a: j = jq (same twiddles for all b)
    const int jt = jq << (12 - 2 * S);
    const float2 w1 = tw[jt], w2 = tw[2 * jt], w3 = tw[3 * jt];
    #pragma unroll
    for (int b = 0; b < 4; ++b) {
      x[1][b] = cmulc(x[1][b], w1);
      x[2][b] = cmulc(x[2][b], w2);
      x[3][b] = cmulc(x[3][b], w3);
      bf4_dit(x[0][b], x[1][b], x[2][b], x[3][b]);
    }
    // stage S+1 over b: j' = a*M + jq
    #pragma unroll
    for (int a = 0; a < 4; ++a) {
      const int jt2 = (a * M + jq) << (10 - 2 * S);
      x[a][1] = cmulc(x[a][1], tw[jt2]);
      x[a][2] = cmulc(x[a][2], tw[2 * jt2]);
      x[a][3] = cmulc(x[a][3], tw[3 * jt2]);
      bf4_dit(x[a][0], x[a][1], x[a][2], x[a][3]);
    }
    #pragma unroll
    for (int a = 0; a < 4; ++a)
      #pragma unroll
      for (int b = 0; b < 4; ++b)
        A[pb + PADOFF((b << (2 * S + 2)) + (a << (2 * S)))] = x[a][b];
  }
}

// DIF forward: natural-order input -> base-4 digit-reversed output (Y[k] at rev4_14(k))
__device__ __forceinline__ void fft_dif4(float2* A, const float2* __restrict__ tw, int tid) {
  fft_dif4_pair<6>(A, tw, tid);
  fft_dif4_pair<4>(A, tw, tid);
  fft_dif4_pair<2>(A, tw, tid);
  fft_dif4_last(A, tid);
  __syncthreads();
}

// DIT inverse (conjugate twiddles, unnormalized): digit-reversed input -> natural output
__device__ __forceinline__ void fft_dit4_inv(float2* A, const float2* __restrict__ tw, int tid) {
  fft_dit4_first(A, tid);
  fft_dit4_pair<1>(A, tw, tid);
  fft_dit4_pair<3>(A, tw, tid);
  fft_dit4_pair<5>(A, tw, tid);
  __syncthreads();
}

// ---- common small kernels ---------------------------------------------------

__global__ void init_kernel(unsigned long long* best, float* acc) {
  int i = blockIdx.x * blockDim.x + threadIdx.x;
  if (i < BB) best[i] = 0ull;
  if (i < 4)  acc[i]  = 0.f;
}

__global__ void twid_kernel(float2* tw, float2* w32) {
  int i = blockIdx.x * 256 + threadIdx.x;
  if (i < FM) {
    double a = -2.0 * 3.14159265358979323846 * (double)i / (double)FM;
    tw[i] = make_float2((float)cos(a), (float)sin(a));
  }
  if (i < 8192) {
    double a = -2.0 * 3.14159265358979323846 * (double)i / (double)(2 * FM);
    w32[i] = make_float2((float)cos(a), (float)sin(a));
  }
}

__global__ void astf_kernel(const float* __restrict__ p, const float* __restrict__ t,
                            float* __restrict__ acc) {
  int gid = blockIdx.x * blockDim.x + threadIdx.x;
  int stride = gridDim.x * blockDim.x;
  const float4* p4 = (const float4*)p;
  const float4* t4 = (const float4*)t;
  const int n4 = (BB * L1) / 4;
  float s = 0.f;
  for (int i = gid; i < n4; i += stride) {
    float4 a = p4[i], b = t4[i];
    float dx = a.x - b.x, dy = a.y - b.y, dz = a.z - b.z, dw = a.w - b.w;
    s += dx * dx + dy * dy + dz * dz + dw * dw;
  }
  s = blockReduceSum256(s);
  if (threadIdx.x == 0) atomicAdd(&acc[0], s);
}

// ---- FUSED FFT pipeline: astf-MSE + conv (circ corr @16384) + cc (rfft-32768)
// One block handles 2 batches end-to-end. R13 = R10's proven pipefft structure
// (conv repack via global store + L2-hot reload; register staging across
// barriers spills ~21 MB/dispatch per R11/R12) + astf-MSE fusion (R12's
// proven ~11 us win: pred row read anyway, true row added, one atomic/block).
__global__ __launch_bounds__(512, 2) void pipefft_kernel(const float* __restrict__ pred,
                                                         const float* __restrict__ truea,
                                                         const float* __restrict__ egf,
                                                         const float* __restrict__ target,
                                                         const float2* __restrict__ tw,
                                                         const float2* __restrict__ w32,
                                                         float* convbuf,
                                                         float4* __restrict__ spec,
                                                         unsigned long long* __restrict__ best,
                                                         float* __restrict__ acc) {
  __shared__ float2 A[NPAD];
  __shared__ unsigned long long sbest[8];
  __shared__ float swsum[8];
  const int tid = threadIdx.x;
  float4* sp = spec + (size_t)blockIdx.x * 8192;
  float asum = 0.f;

  for (int half = 0; half < 2; ++half) {
    const int b = blockIdx.x * 2 + half;
    const float* pb = pred  + (size_t)b * L1;
    const float* tb = truea + (size_t)b * L1;
    const float* eb = egf   + (size_t)b * L2;
    float* cr       = convbuf + (size_t)b * CROW;
    const float* tr = target  + (size_t)b * TLEN;

    // ===== conv pack (+ fused astf MSE): z = pred + i*egf ====================
    for (int i = tid; i < FM; i += 512) {
      float pv = pb[i];
      float d  = pv - tb[i];
      asum += d * d;
      A[IDX(i)] = make_float2(pv, (i < L2) ? eb[i] : 0.f);
    }

    fft_dif4(A, tw, tid);

    for (int rr = 0; rr < 16; ++rr) {
      const int k = tid * 16 + rr;
      if (k == 0) {
        float2 z0 = A[IDX(0)];
        A[IDX(0)] = make_float2(z0.x * z0.y, 0.f);
        const int p = IDX(2);                 // rev4(8192) == 2
        float2 zn = A[p];
        A[p] = make_float2(zn.x * zn.y, 0.f);
      } else {
        const int p = IDX(rev4_14(k)), q = IDX(rev4_14(FM - k));
        float2 z1 = A[p], z2 = A[q];
        float pr = 0.5f * (z1.x + z2.x), pi = 0.5f * (z1.y - z2.y);   // PRED[k]
        float er = 0.5f * (z1.y + z2.y), ei = 0.5f * (z2.x - z1.x);   // EGF[k]
        float sr = pr * er + pi * ei;                                  // S = PRED*conj(EGF)
        float si = pi * er - pr * ei;
        A[p] = make_float2(sr, si);
        A[q] = make_float2(sr, -si);
      }
    }

    fft_dit4_inv(A, tw, tid);   // A[IDX(n)].x = conv[n]*FM, natural order

    // store conv row; __syncthreads drains stores; L2 holds this block's row
    const float sc = 1.f / (float)FM;
    for (int i = tid; i < CL; i += 512) cr[i] = A[IDX(i)].x * sc;
    __syncthreads();

    // ===== cc part: rfft-32768 of conv & target via packed 16384 FFTs =====
    // conv packed even/odd (L2-hot re-read; CROW even -> 8B-aligned float2)
    for (int i = tid; i < 7168; i += 512)
      A[IDX(i)] = *(const float2*)(cr + 2 * i);
    for (int i = 7168 + tid; i < FM; i += 512) {
      float re = (i == 7168) ? cr[14336] : 0.f;   // 2*7168 == 14336 == CL-1
      A[IDX(i)] = make_float2(re, 0.f);
    }
    fft_dif4(A, tw, tid);                     // Yc of packed conv

    // stash Yc in glue order (coalesced float4): sp[(rr<<9)|tid] =
    // (Yc[rev4(k)], Yc[rev4(FM-k)]) for k = tid*16+rr; (0,8192) in k==0 slot
    #pragma unroll 1
    for (int rr = 0; rr < 16; ++rr) {
      const int k = tid * 16 + rr;
      const int s = (rr << 9) | tid;
      float2 ya, yb;
      if (k == 0) { ya = A[IDX(0)]; yb = A[IDX(2)]; }   // rev4(8192) == 2
      else        { ya = A[IDX(rev4_14(k))]; yb = A[IDX(rev4_14(FM - k))]; }
      sp[s] = make_float4(ya.x, ya.y, yb.x, yb.y);
    }
    __syncthreads();

    // target packed even/odd (TLEN odd -> rows misaligned for odd b; scalar)
    for (int i = tid; i < FM; i += 512) {
      int g = 2 * i;
      float re = (g     < TLEN) ? tr[g]     : 0.f;
      float im = (g + 1 < TLEN) ? tr[g + 1] : 0.f;
      A[IDX(i)] = make_float2(re, im);
    }
    fft_dif4(A, tw, tid);                                    // A = Yt

    // glue: build y' spectrum of the packed cc sequence, in digit-rev slots
    #pragma unroll 1
    for (int rr = 0; rr < 16; ++rr) {
      const int k = tid * 16 + rr;
      const int s = (rr << 9) | tid;
      const float4 y4 = sp[s];                        // coalesced
      if (k == 0) {
        float2 yc0 = make_float2(y4.x, y4.y), yt0 = A[IDX(0)];
        float X0 = yc0.x + yc0.y, XM = yc0.x - yc0.y;
        float T0 = yt0.x + yt0.y, TM = yt0.x - yt0.y;
        float C0 = X0 * T0, CM = XM * TM;
        A[IDX(0)] = make_float2(0.5f * (C0 + CM), 0.5f * (C0 - CM));
        // bin 8192 (self-paired): rev4(8192) == 2
        float2 yc = make_float2(y4.z, y4.w), yt = A[IDX(2)];
        float cr8 = yc.x * yt.x + yc.y * yt.y;
        float ci8 = yc.x * yt.y - yc.y * yt.x;
        A[IDX(2)] = make_float2(cr8, -ci8);
      } else {
        const int p = IDX(rev4_14(k)), q = IDX(rev4_14(FM - k));
        const float2 w = w32[k];                        // e^{-2*pi*i*k/32768}
        // X[k], X[M-k] from Yc (coalesced stash)
        float2 ya = make_float2(y4.x, y4.y), yb = make_float2(y4.z, y4.w);
        float xer = 0.5f * (ya.x + yb.x), xei = 0.5f * (ya.y - yb.y);
        float dr  = 0.5f * (ya.x - yb.x), di  = 0.5f * (ya.y + yb.y);
        float xo_r = di, xo_i = -dr;                    // Xo = -i*D
        float wxr = w.x * xo_r - w.y * xo_i, wxi = w.x * xo_i + w.y * xo_r;
        float Xkr = xer + wxr, Xki = xei + wxi;
        float Xmr = xer - wxr, Xmi = -(xei - wxi);      // X[M-k] = conj(Xe - W*Xo)
        // T[k], T[M-k] from Yt
        float2 ta = A[p], tb2 = A[q];
        float ter = 0.5f * (ta.x + tb2.x), tei = 0.5f * (ta.y - tb2.y);
        float er2 = 0.5f * (ta.x - tb2.x), ei2 = 0.5f * (ta.y + tb2.y);
        float to_r = ei2, to_i = -er2;
        float twr = w.x * to_r - w.y * to_i, twi = w.x * to_i + w.y * to_r;
        float Tkr = ter + twr, Tki = tei + twi;
        float Tmr = ter - twr, Tmi = -(tei - twi);
        // C[k]=X[k]*conj(T[k]); C[M-k]=X[M-k]*conj(T[M-k])
        float Ckr = Xkr * Tkr + Xki * Tki, Cki = Xki * Tkr - Xkr * Tki;
        float Cmr = Xmr * Tmr + Xmi * Tmi, Cmi = Xmi * Tmr - Xmr * Tmi;
        // y'[k] = Ce + i*V*D, V = conj(w)
        float aer = 0.5f * (Ckr + Cmr), aei = 0.5f * (Cki - Cmi);
        float bdr = 0.5f * (Ckr - Cmr), bdi = 0.5f * (Cki + Cmi);
        float cor_ = w.x * bdr + w.y * bdi, coi = w.x * bdi - w.y * bdr;
        A[p] = make_float2(aer - coi, aei + cor_);
        // y'[M-k] = Ce2 + i*(-w)*D2
        float a2r = 0.5f * (Cmr + Ckr), a2i = 0.5f * (Cmi - Cki);
        float d2r = 0.5f * (Cmr - Ckr), d2i = 0.5f * (Cmi + Cki);
        float c2r = -(w.x * d2r - w.y * d2i), c2i = -(w.x * d2i + w.y * d2r);
        A[q] = make_float2(a2r - c2i, a2i + c2r);
      }
    }

    fft_dit4_inv(A, tw, tid);  // A[n] = (cc[2n], cc[2n+1]) * FM

    // argmax with j->np mapping: j<=14336 -> np=j ; (14336,18432) dead ; j>=18432 -> np=j-4095
    unsigned long long pk = 0ull;
    for (int i = tid; i < FM; i += 512) {
      float2 v2 = A[IDX(i)];
      int j0 = 2 * i, j1 = 2 * i + 1;
      if (j0 <= 14336) {
        unsigned long long p = ((unsigned long long)fkey(v2.x) << 32)
                             | (unsigned long long)(0xFFFFFFFFu - (unsigned)j0);
        if (p > pk) pk = p;
      } else if (j0 >= 18432) {
        unsigned long long p = ((unsigned long long)fkey(v2.x) << 32)
                             | (unsigned long long)(0xFFFFFFFFu - (unsigned)(j0 - 4095));
        if (p > pk) pk = p;
      }
      if (j1 <= 14336) {
        unsigned long long p = ((unsigned long long)fkey(v2.y) << 32)
                             | (unsigned long long)(0xFFFFFFFFu - (unsigned)j1);
        if (p > pk) pk = p;
      } else if (j1 >= 18432) {
        unsigned long long p = ((unsigned long long)fkey(v2.y) << 32)
                             | (unsigned long long)(0xFFFFFFFFu - (unsigned)(j1 - 4095));
        if (p > pk) pk = p;
      }
    }
    #pragma unroll
    for (int o = 32; o > 0; o >>= 1) {
      unsigned long long q = __shfl_down(pk, o, 64);
      if (q > pk) pk = q;
    }
    if ((tid & 63) == 0) sbest[tid >> 6] = pk;
    __syncthreads();
    if (tid == 0) {
      #pragma unroll
      for (int i = 1; i < 8; ++i) if (sbest[i] > pk) pk = sbest[i];
      best[b] = pk;
    }
    __syncthreads();
  }

  // ===== fused astf MSE reduction (both halves), one atomic per block ========
  #pragma unroll
  for (int o = 32; o > 0; o >>= 1) asum += __shfl_down(asum, o, 64);
  if ((tid & 63) == 0) swsum[tid >> 6] = asum;
  __syncthreads();
  if (tid == 0) {
    float s = 0.f;
    #pragma unroll
    for (int i = 0; i < 8; ++i) s += swsum[i];
    atomicAdd(&acc[0], s);
  }
}

// ---- fallback direct path (proven r3 kernels) -------------------------------

__device__ __forceinline__ void taps4(float* acc, const float4 a, const float4 b,
                                      const float4 e) {
  acc[0] = fmaf(a.x, e.x, acc[0]); acc[0] = fmaf(a.y, e.y, acc[0]);
  acc[0] = fmaf(a.z, e.z, acc[0]); acc[0] = fmaf(a.w, e.w, acc[0]);
  acc[1] = fmaf(a.y, e.x, acc[1]); acc[1] = fmaf(a.z, e.y, acc[1]);
  acc[1] = fmaf(a.w, e.z, acc[1]); acc[1] = fmaf(b.x, e.w, acc[1]);
  acc[2] = fmaf(a.z, e.x, acc[2]); acc[2] = fmaf(a.w, e.y, acc[2]);
  acc[2] = fmaf(b.x, e.z, acc[2]); acc[2] = fmaf(b.y, e.w, acc[2]);
  acc[3] = fmaf(a.w, e.x, acc[3]); acc[3] = fmaf(b.x, e.y, acc[3]);
  acc[3] = fmaf(b.y, e.z, acc[3]); acc[3] = fmaf(b.z, e.w, acc[3]);
}

__device__ __forceinline__ float4 gload4(const float* __restrict__ cr, int g) {
  if (g >= 0 && g + 3 < CL) return *(const float4*)(cr + g);
  float4 v;
  int g0 = min(max(g,     0), CL - 1);
  int g1 = min(max(g + 1, 0), CL - 1);
  int g2 = min(max(g + 2, 0), CL - 1);
  int g3 = min(max(g + 3, 0), CL - 1);
  v.x = (g     >= 0 && g     < CL) ? cr[g0] : 0.f;
  v.y = (g + 1 >= 0 && g + 1 < CL) ? cr[g1] : 0.f;
  v.z = (g + 2 >= 0 && g + 2 < CL) ? cr[g2] : 0.f;
  v.w = (g + 3 >= 0 && g + 3 < CL) ? cr[g3] : 0.f;
  return v;
}

__global__ __launch_bounds__(256) void conv_kernel(const float* __restrict__ pred,
                                                   const float* __restrict__ egf,
                                                   float* __restrict__ convbuf) {
  const int b = blockIdx.y;
  const int x = blockIdx.x;
  const int tid = threadIdx.x;
  const float* pb = pred + (size_t)b * L1;
  const float* eg = egf  + (size_t)b * L2;
  float* cr = convbuf + (size_t)b * CROW;

  if (x == 7) {
    float s = 0.f;
    const int k0 = tid * 8;
    #pragma unroll
    for (int j = 0; j < 8; ++j) s += pb[PADL + k0 + j] * eg[k0 + j];
    s = blockReduceSum256(s);
    if (tid == 0) cr[PADL] = s;
    return;
  }

  const int m = x * 2048 + tid * 8;
  const float* cp = pb + m;
  float accA[4] = {0.f,0.f,0.f,0.f};
  float accB[4] = {0.f,0.f,0.f,0.f};
  float4 w0 = *(const float4*)(cp);
  float4 w1 = *(const float4*)(cp + 4);
  float4 w2 = *(const float4*)(cp + 8);

  #pragma unroll 4
  for (int k = 0; k < L2 - 4; k += 4) {
    const float4 e  = *(const float4*)(eg + k);
    const float4 nx = *(const float4*)(cp + k + 12);
    taps4(accA, w0, w1, e);
    taps4(accB, w1, w2, e);
    w0 = w1; w1 = w2; w2 = nx;
  }
  {
    const float4 e = *(const float4*)(eg + (L2 - 4));
    taps4(accA, w0, w1, e);
    taps4(accB, w1, w2, e);
  }

  *(float4*)(cr + m)     = make_float4(accA[0], accA[1], accA[2], accA[3]);
  *(float4*)(cr + m + 4) = make_float4(accB[0], accB[1], accB[2], accB[3]);
}

__global__ __launch_bounds__(256) void cc_kernel(const float* __restrict__ convbuf,
                                                 const float* __restrict__ target,
                                                 unsigned long long* __restrict__ best) {
  __shared__ unsigned long long sbest[4];
  const int b   = blockIdx.y;
  const int m0  = blockIdx.x * 2048;
  const int tid = threadIdx.x;
  const float* cr = convbuf + (size_t)b * CROW;
  const float* tr = target  + (size_t)b * TLEN;
  const int m    = m0 + tid * 8;
  const int gofs = m - PADL;

  float accA[4] = {0.f,0.f,0.f,0.f};
  float accB[4] = {0.f,0.f,0.f,0.f};

  const int t1raw = PADL - m0;
  const int t1    = t1raw > 0 ? t1raw : 0;
  const int t2    = PADL + CL - m0 - 2047;
  int tIntHi      = (t2 - 16) & ~3;
  if (tIntHi > 14332) tIntHi = 14332;
  if (tIntHi < t1)    tIntHi = t1;
  int e0 = (t1raw - 2047) > 0 ? ((t1raw - 2047) & ~3) : 0;
  const int eH = min(TLEN, NCC - m0);

  if (e0 < t1) {
    float4 w0 = gload4(cr, gofs + e0);
    float4 w1 = gload4(cr, gofs + e0 + 4);
    float4 w2 = gload4(cr, gofs + e0 + 8);
    #pragma unroll 2
    for (int t = e0; t < t1; t += 4) {
      const float4 e  = *(const float4*)(tr + t);
      const float4 nx = gload4(cr, gofs + t + 12);
      taps4(accA, w0, w1, e);
      taps4(accB, w1, w2, e);
      w0 = w1; w1 = w2; w2 = nx;
    }
  }

  if (t1 < tIntHi) {
    const float* cp = cr + gofs;
    float4 w0 = *(const float4*)(cp + t1);
    float4 w1 = *(const float4*)(cp + t1 + 4);
    float4 w2 = *(const float4*)(cp + t1 + 8);
    #pragma unroll 4
    for (int t = t1; t < tIntHi; t += 4) {
      const float4 e  = *(const float4*)(tr + t);
      const float4 nx = *(const float4*)(cp + t + 12);
      taps4(accA, w0, w1, e);
      taps4(accB, w1, w2, e);
      w0 = w1; w1 = w2; w2 = nx;
    }
  }

  if (tIntHi < eH) {
    float4 w0 = gload4(cr, gofs + tIntHi);
    float4 w1 = gload4(cr, gofs + tIntHi + 4);
    float4 w2 = gload4(cr, gofs + tIntHi + 8);
    #pragma unroll 2
    for (int t = tIntHi; t < eH; t += 4) {
      float4 e;
      e.x = (t     < TLEN) ? tr[t]     : 0.f;
      e.y = (t + 1 < TLEN) ? tr[t + 1] : 0.f;
      e.z = (t + 2 < TLEN) ? tr[t + 2] : 0.f;
      e.w = (t + 3 < TLEN) ? tr[t + 3] : 0.f;
      const float4 nx = gload4(cr, gofs + t + 12);
      taps4(accA, w0, w1, e);
      taps4(accB, w1, w2, e);
      w0 = w1; w1 = w2; w2 = nx;
    }
  }

  unsigned long long pk = 0ull;
  #pragma unroll
  for (int j = 0; j < 4; ++j) {
    int mm = m + j;
    if (mm < NCC) {
      int np = (mm >= PADL) ? (mm - PADL) : (mm + CL);
      unsigned long long p = ((unsigned long long)fkey(accA[j]) << 32)
                           | (unsigned long long)(0xFFFFFFFFu - (unsigned)np);
      if (p > pk) pk = p;
    }
    mm = m + 4 + j;
    if (mm < NCC) {
      int np = (mm >= PADL) ? (mm - PADL) : (mm + CL);
      unsigned long long p = ((unsigned long long)fkey(accB[j]) << 32)
                           | (unsigned long long)(0xFFFFFFFFu - (unsigned)np);
      if (p > pk) pk = p;
    }
  }
  #pragma unroll
  for (int o = 32; o > 0; o >>= 1) {
    unsigned long long q = __shfl_down(pk, o, 64);
    if (q > pk) pk = q;
  }
  if ((tid & 63) == 0) sbest[tid >> 6] = pk;
  __syncthreads();
  if (tid == 0) {
    #pragma unroll
    for (int i = 1; i < 4; ++i) if (sbest[i] > pk) pk = sbest[i];
    atomicMax(best + b, pk);
  }
}

__global__ void closs_kernel(const float* __restrict__ convbuf,
                             const float* __restrict__ target,
                             const unsigned long long* __restrict__ best,
                             float* __restrict__ acc) {
  const int b = blockIdx.x;
  const int np = (int)(0xFFFFFFFFu - (unsigned)(best[b] & 0xFFFFFFFFull));
  const int shift = np - PADL;
  const int jj = CSTART + threadIdx.x;
  int pos = jj + shift;
  if (pos < 0) pos += CL; else if (pos >= CL) pos -= CL;
  float d = convbuf[(size_t)b * CROW + pos] - target[(size_t)b * TLEN + jj];
  float s = blockReduceSum256(d * d);
  if (threadIdx.x == 0) atomicAdd(&acc[1], s);
}

__global__ void fin_kernel(const float* __restrict__ acc, float* __restrict__ out) {
  if (threadIdx.x == 0 && blockIdx.x == 0) {
    float la = acc[0] / (float)((long)BB * L1);
    float lc = acc[1] / (float)(BB * CROP);
    out[0] = la + lc;
    out[1] = la;
    out[2] = lc;
  }
}

// ---- launch -----------------------------------------------------------------

extern "C" void kernel_launch(void* const* d_in, const int* in_sizes, int n_in,
                              void* d_out, int out_size, void* d_ws, size_t ws_size,
                              hipStream_t stream) {
  (void)in_sizes; (void)n_in; (void)out_size;
  const float* pred   = (const float*)d_in[0];
  const float* truea  = (const float*)d_in[1];
  const float* egf    = (const float*)d_in[2];
  const float* target = (const float*)d_in[3];
  float* out = (float*)d_out;

  char* ws = (char*)d_ws;
  const size_t off_best = (size_t)BB * CROW * 4;          // 29,368,320
  const size_t off_acc  = off_best + (size_t)BB * 8;
  const size_t off_tw   = off_acc + 256;
  const size_t off_w32  = off_tw + (size_t)FM * 8;
  const size_t off_spec = off_w32 + (size_t)8192 * 8;
  const size_t needed   = off_spec + (size_t)256 * FM * 8; // ~63.1 MB

  float* convbuf            = (float*)ws;
  unsigned long long* best  = (unsigned long long*)(ws + off_best);
  float* acc                = (float*)(ws + off_acc);
  float2* tw                = (float2*)(ws + off_tw);
  float2* w32               = (float2*)(ws + off_w32);
  float4* spec              = (float4*)(ws + off_spec);

  init_kernel<<<2, 256, 0, stream>>>(best, acc);

  if (ws_size >= needed) {
    twid_kernel<<<64, 256, 0, stream>>>(tw, w32);
    pipefft_kernel<<<BB / 2, 512, 0, stream>>>(pred, truea, egf, target, tw, w32,
                                               convbuf, spec, best, acc);
  } else {
    astf_kernel<<<1024, 256, 0, stream>>>(pred, truea, acc);
    conv_kernel<<<dim3(8, BB), 256, 0, stream>>>(pred, egf, convbuf);
    cc_kernel<<<dim3(15, BB), 256, 0, stream>>>(convbuf, target, best);
  }

  closs_kernel<<<dim3(BB), 256, 0, stream>>>(convbuf, target, best, acc);
  fin_kernel<<<1, 64, 0, stream>>>(acc, out);
}

// Round 14
// 226.935 us; speedup vs baseline: 1.1121x; 1.0216x over previous
//
#include <hip/hip_runtime.h>

// Problem constants
#define BB     512
#define L1     16384
#define L2     2048
#define CL     14337      // conv_len = L1 - L2 + 1
#define NCC    28673      // 2*CL - 1 (number of cc lags)
#define PADL   14336      // CL - 1
#define CROW   14340      // padded conv row stride (floats, %4==0)
#define CROP   256
#define CSTART 7040       // (CL - CROP)/2
#define TLEN   14337      // target row length
#define FM     16384      // complex FFT size
#define LOGM   14

// Padded LDS indexing: phys = i + (i>>4).
#define NPAD  17408       // 16384 + 16384/16
#define IDX(i) ((i) + ((i) >> 4))
// For digit-aligned offsets (base%16 + off%16 <= 15): IDX(base+off) ==
// IDX(base) + PADOFF(off) exactly, with PADOFF compile-time (verified per-S).
#define PADOFF(o) ((o) + ((o) >> 4))

// base-4 digit reversal of a 14-bit index (7 digits)
__device__ __forceinline__ int rev4_14(int x) {
  int b = (int)(__brev((unsigned)x) >> 18);
  return ((b & 0x1555) << 1) | ((b >> 1) & 0x1555);
}

__device__ __forceinline__ unsigned int fkey(float f) {
  unsigned int b = __float_as_uint(f);
  return b ^ ((b & 0x80000000u) ? 0xFFFFFFFFu : 0x80000000u);  // order-preserving
}

__device__ __forceinline__ float blockReduceSum256(float v) {
  #pragma unroll
  for (int o = 32; o > 0; o >>= 1) v += __shfl_down(v, o, 64);
  __shared__ float sws[4];
  if ((threadIdx.x & 63) == 0) sws[threadIdx.x >> 6] = v;
  __syncthreads();
  float r = 0.f;
  if (threadIdx.x == 0) r = sws[0] + sws[1] + sws[2] + sws[3];
  return r;
}

// ---------------- complex helpers -------------------------------------------
__device__ __forceinline__ float2 cmul(const float2 w, const float2 u) {
  return make_float2(w.x * u.x - w.y * u.y, w.x * u.y + w.y * u.x);
}
__device__ __forceinline__ float2 cmulc(const float2 x, const float2 w) {  // x*conj(w)
  return make_float2(w.x * x.x + w.y * x.y, w.x * x.y - w.y * x.x);
}

__device__ __forceinline__ void bf4_dif(float2& x0, float2& x1, float2& x2, float2& x3) {
  float t0r = x0.x + x2.x, t0i = x0.y + x2.y;
  float t1r = x1.x + x3.x, t1i = x1.y + x3.y;
  float t2r = x0.x - x2.x, t2i = x0.y - x2.y;
  float t3r = x1.y - x3.y, t3i = x3.x - x1.x;   // -i*(x1-x3)
  x0 = make_float2(t0r + t1r, t0i + t1i);
  x1 = make_float2(t2r + t3r, t2i + t3i);
  x2 = make_float2(t0r - t1r, t0i - t1i);
  x3 = make_float2(t2r - t3r, t2i - t3i);
}

__device__ __forceinline__ void bf4_dit(float2& x0, float2& x1, float2& x2, float2& x3) {
  float s0r = x0.x + x2.x, s0i = x0.y + x2.y;
  float s1r = x0.x - x2.x, s1i = x0.y - x2.y;
  float s2r = x1.x + x3.x, s2i = x1.y + x3.y;
  float s3r = x3.y - x1.y, s3i = x1.x - x3.x;   // i*(x1-x3)
  x0 = make_float2(s0r + s2r, s0i + s2i);
  x1 = make_float2(s1r + s3r, s1i + s3i);
  x2 = make_float2(s0r - s2r, s0i - s2i);
  x3 = make_float2(s1r - s3r, s1i - s3i);
}

// ---------------- radix-16 phase FFT cores (512 threads, padded LDS) ---------
// R7 structure (proven: 128 VGPR) + PADOFF base+immediate addressing.
// 1024-thread variants are dead: compiler pins VGPR=64 and spills (R5/R6/R8).
// Register-staging data across barriers is also dead: even 16 VGPRs of stash
// spilled ~21 MB/dispatch (R11/R12) -> conv repack uses the L2-hot global
// round-trip (R10's proven pattern).
template <int S>
__device__ __forceinline__ void fft_dif4_pair(float2* A, const float2* __restrict__ tw,
                                              int tid) {
  __syncthreads();
  constexpr int Q  = 1 << (2 * S - 2);
  constexpr int TS = 12 - 2 * S;
  #pragma unroll 1
  for (int r = 0; r < 2; ++r) {
    const int bf = (r << 9) | tid;
    const int jq = bf & (Q - 1);
    const int hi = bf >> (2 * S - 2);
    const int pb = IDX((hi << (2 * S + 2)) | jq);
    float2 x[4][4];   // x[a][b] at base + a*4^S + b*4^(S-1)
    #pragma unroll
    for (int a = 0; a < 4; ++a)
      #pragma unroll
      for (int b = 0; b < 4; ++b)
        x[a][b] = A[pb + PADOFF((a << (2 * S)) + (b << (2 * S - 2)))];
    // stage S over a (twiddle j = b*Q + jq)
    #pragma unroll
    for (int b = 0; b < 4; ++b) {
      bf4_dif(x[0][b], x[1][b], x[2][b], x[3][b]);
      const int jt = (b * Q + jq) << TS;
      x[1][b] = cmul(tw[jt],     x[1][b]);
      x[2][b] = cmul(tw[2 * jt], x[2][b]);
      x[3][b] = cmul(tw[3 * jt], x[3][b]);
    }
    // stage S-1 over b (twiddle j2 = jq, shared across a)
    const int jt2 = jq << (14 - 2 * S);
    const float2 v1 = tw[jt2], v2 = tw[2 * jt2], v3 = tw[3 * jt2];
    #pragma unroll
    for (int a = 0; a < 4; ++a) {
      bf4_dif(x[a][0], x[a][1], x[a][2], x[a][3]);
      x[a][1] = cmul(v1, x[a][1]);
      x[a][2] = cmul(v2, x[a][2]);
      x[a][3] = cmul(v3, x[a][3]);
    }
    #pragma unroll
    for (int a = 0; a < 4; ++a)
      #pragma unroll
      for (int b = 0; b < 4; ++b)
        A[pb + PADOFF((a << (2 * S)) + (b << (2 * S - 2)))] = x[a][b];
  }
}

// Final DIF stage s=0 (twiddles == 1). i0%16 in {0,4,8,12} -> IDX(i0)+j exact.
__device__ __forceinline__ void fft_dif4_last(float2* A, int tid) {
  __syncthreads();
  for (int r = 0; r < 8; ++r) {
    const int p0 = IDX((((r << 9) | tid) << 2));
    float2 x0 = A[p0], x1 = A[p0 + 1], x2 = A[p0 + 2], x3 = A[p0 + 3];
    bf4_dif(x0, x1, x2, x3);
    A[p0] = x0; A[p0 + 1] = x1; A[p0 + 2] = x2; A[p0 + 3] = x3;
  }
}

// First DIT stage s=0 (twiddles == 1)
__device__ __forceinline__ void fft_dit4_first(float2* A, int tid) {
  __syncthreads();
  for (int r = 0; r < 8; ++r) {
    const int p0 = IDX((((r << 9) | tid) << 2));
    float2 x0 = A[p0], x1 = A[p0 + 1], x2 = A[p0 + 2], x3 = A[p0 + 3];
    bf4_dit(x0, x1, x2, x3);
    A[p0] = x0; A[p0 + 1] = x1; A[p0 + 2] = x2; A[p0 + 3] = x3;
  }
}

// Merged DIT stage pair (S, S+1), S in {1,3,5}
template <int S>
__device__ __forceinline__ void fft_dit4_pair(float2* A, const float2* __restrict__ tw,
                                              int tid) {
  __syncthreads();
  constexpr int M = 1 << (2 * S);
  #pragma unroll 1
  for (int r = 0; r < 2; ++r) {
    const int bf = (r << 9) | tid;
    const int jq = bf & (M - 1);
    const int hi = bf >> (2 * S);
    const int pb = IDX((hi << (2 * S + 4)) | jq);
    float2 x[4][4];   // x[a][b] at base + b*4M + a*M
    #pragma unroll
    for (int a = 0; a < 4; ++a)
      #pragma unroll
      for (int b = 0; b < 4; ++b)
        x[a][b] = A[pb + PADOFF((b << (2 * S + 2)) + (a << (2 * S)))];
    // stage S over a: j = jq (same twiddles for all b)
    const int jt = jq << (12 - 2 * S);
    const float2 w1 = tw[jt], w2 = tw[2 * jt], w3 = tw[3 * jt];
    #pragma unroll
    for (int b = 0; b < 4; ++b) {
      x[1][b] = cmulc(x[1][b], w1);
      x[2][b] = cmulc(x[2][b], w2);
      x[3][b] = cmulc(x[3][b], w3);
      bf4_dit(x[0][b], x[1][b], x[2][b], x[3][b]);
    }
    // stage S+1 over b: j' = a*M + jq
    #pragma unroll
    for (int a = 0; a < 4; ++a) {
      const int jt2 = (a * M + jq) << (10 - 2 * S);
      x[a][1] = cmulc(x[a][1], tw[jt2]);
      x[a][2] = cmulc(x[a][2], tw[2 * jt2]);
      x[a][3] = cmulc(x[a][3], tw[3 * jt2]);
      bf4_dit(x[a][0], x[a][1], x[a][2], x[a][3]);
    }
    #pragma unroll
    for (int a = 0; a < 4; ++a)
      #pragma unroll
      for (int b = 0; b < 4; ++b)
        A[pb + PADOFF((b << (2 * S + 2)) + (a << (2 * S)))] = x[a][b];
  }
}

// DIF forward: natural-order input -> base-4 digit-reversed output (Y[k] at rev4_14(k))
__device__ __forceinline__ void fft_dif4(float2* A, const float2* __restrict__ tw, int tid) {
  fft_dif4_pair<6>(A, tw, tid);
  fft_dif4_pair<4>(A, tw, tid);
  fft_dif4_pair<2>(A, tw, tid);
  fft_dif4_last(A, tid);
  __syncthreads();
}

// DIT inverse (conjugate twiddles, unnormalized): digit-reversed input -> natural output
__device__ __forceinline__ void fft_dit4_inv(float2* A, const float2* __restrict__ tw, int tid) {
  fft_dit4_first(A, tid);
  fft_dit4_pair<1>(A, tw, tid);
  fft_dit4_pair<3>(A, tw, tid);
  fft_dit4_pair<5>(A, tw, tid);
  __syncthreads();
}

// ---- common small kernels ---------------------------------------------------

__global__ void init_kernel(unsigned long long* best, float* acc) {
  int i = blockIdx.x * blockDim.x + threadIdx.x;
  if (i < BB) best[i] = 0ull;
  if (i < 4)  acc[i]  = 0.f;
}

__global__ void twid_kernel(float2* tw, float2* w32) {
  int i = blockIdx.x * 256 + threadIdx.x;
  if (i < FM) {
    double a = -2.0 * 3.14159265358979323846 * (double)i / (double)FM;
    tw[i] = make_float2((float)cos(a), (float)sin(a));
  }
  if (i < 8192) {
    double a = -2.0 * 3.14159265358979323846 * (double)i / (double)(2 * FM);
    w32[i] = make_float2((float)cos(a), (float)sin(a));
  }
}

__global__ void astf_kernel(const float* __restrict__ p, const float* __restrict__ t,
                            float* __restrict__ acc) {
  int gid = blockIdx.x * blockDim.x + threadIdx.x;
  int stride = gridDim.x * blockDim.x;
  const float4* p4 = (const float4*)p;
  const float4* t4 = (const float4*)t;
  const int n4 = (BB * L1) / 4;
  float s = 0.f;
  for (int i = gid; i < n4; i += stride) {
    float4 a = p4[i], b = t4[i];
    float dx = a.x - b.x, dy = a.y - b.y, dz = a.z - b.z, dw = a.w - b.w;
    s += dx * dx + dy * dy + dz * dz + dw * dw;
  }
  s = blockReduceSum256(s);
  if (threadIdx.x == 0) atomicAdd(&acc[0], s);
}

// ---- FUSED FFT pipeline: astf-MSE + conv + cc + closs, one block = 2 batches
// R14: closs fused into the tail of each half (best[b] is block-local; conv
// row is L2-hot from this half's store) -> closs dispatch removed in FFT path.
__global__ __launch_bounds__(512, 2) void pipefft_kernel(const float* __restrict__ pred,
                                                         const float* __restrict__ truea,
                                                         const float* __restrict__ egf,
                                                         const float* __restrict__ target,
                                                         const float2* __restrict__ tw,
                                                         const float2* __restrict__ w32,
                                                         float* convbuf,
                                                         float4* __restrict__ spec,
                                                         unsigned long long* __restrict__ best,
                                                         float* __restrict__ acc) {
  __shared__ float2 A[NPAD];
  __shared__ unsigned long long sbest[8];
  __shared__ float swsum[8];
  __shared__ int snp;
  const int tid = threadIdx.x;
  float4* sp = spec + (size_t)blockIdx.x * 8192;
  float asum = 0.f;
  float closs_sum = 0.f;

  for (int half = 0; half < 2; ++half) {
    const int b = blockIdx.x * 2 + half;
    const float* pb = pred  + (size_t)b * L1;
    const float* tb = truea + (size_t)b * L1;
    const float* eb = egf   + (size_t)b * L2;
    float* cr       = convbuf + (size_t)b * CROW;
    const float* tr = target  + (size_t)b * TLEN;

    // ===== conv pack (+ fused astf MSE): z = pred + i*egf ====================
    for (int i = tid; i < FM; i += 512) {
      float pv = pb[i];
      float d  = pv - tb[i];
      asum += d * d;
      A[IDX(i)] = make_float2(pv, (i < L2) ? eb[i] : 0.f);
    }

    fft_dif4(A, tw, tid);

    for (int rr = 0; rr < 16; ++rr) {
      const int k = tid * 16 + rr;
      if (k == 0) {
        float2 z0 = A[IDX(0)];
        A[IDX(0)] = make_float2(z0.x * z0.y, 0.f);
        const int p = IDX(2);                 // rev4(8192) == 2
        float2 zn = A[p];
        A[p] = make_float2(zn.x * zn.y, 0.f);
      } else {
        const int p = IDX(rev4_14(k)), q = IDX(rev4_14(FM - k));
        float2 z1 = A[p], z2 = A[q];
        float pr = 0.5f * (z1.x + z2.x), pi = 0.5f * (z1.y - z2.y);   // PRED[k]
        float er = 0.5f * (z1.y + z2.y), ei = 0.5f * (z2.x - z1.x);   // EGF[k]
        float sr = pr * er + pi * ei;                                  // S = PRED*conj(EGF)
        float si = pi * er - pr * ei;
        A[p] = make_float2(sr, si);
        A[q] = make_float2(sr, -si);
      }
    }

    fft_dit4_inv(A, tw, tid);   // A[IDX(n)].x = conv[n]*FM, natural order

    // store conv row; __syncthreads drains stores; L2 holds this block's row
    const float sc = 1.f / (float)FM;
    for (int i = tid; i < CL; i += 512) cr[i] = A[IDX(i)].x * sc;
    __syncthreads();

    // ===== cc part: rfft-32768 of conv & target via packed 16384 FFTs =====
    // conv packed even/odd (L2-hot re-read; CROW even -> 8B-aligned float2)
    for (int i = tid; i < 7168; i += 512)
      A[IDX(i)] = *(const float2*)(cr + 2 * i);
    for (int i = 7168 + tid; i < FM; i += 512) {
      float re = (i == 7168) ? cr[14336] : 0.f;   // 2*7168 == 14336 == CL-1
      A[IDX(i)] = make_float2(re, 0.f);
    }
    fft_dif4(A, tw, tid);                     // Yc of packed conv

    // stash Yc in glue order (coalesced float4): sp[(rr<<9)|tid] =
    // (Yc[rev4(k)], Yc[rev4(FM-k)]) for k = tid*16+rr; (0,8192) in k==0 slot
    #pragma unroll 1
    for (int rr = 0; rr < 16; ++rr) {
      const int k = tid * 16 + rr;
      const int s = (rr << 9) | tid;
      float2 ya, yb;
      if (k == 0) { ya = A[IDX(0)]; yb = A[IDX(2)]; }   // rev4(8192) == 2
      else        { ya = A[IDX(rev4_14(k))]; yb = A[IDX(rev4_14(FM - k))]; }
      sp[s] = make_float4(ya.x, ya.y, yb.x, yb.y);
    }
    __syncthreads();

    // target packed even/odd (TLEN odd -> rows misaligned for odd b; scalar)
    for (int i = tid; i < FM; i += 512) {
      int g = 2 * i;
      float re = (g     < TLEN) ? tr[g]     : 0.f;
      float im = (g + 1 < TLEN) ? tr[g + 1] : 0.f;
      A[IDX(i)] = make_float2(re, im);
    }
    fft_dif4(A, tw, tid);                                    // A = Yt

    // glue: build y' spectrum of the packed cc sequence, in digit-rev slots
    #pragma unroll 1
    for (int rr = 0; rr < 16; ++rr) {
      const int k = tid * 16 + rr;
      const int s = (rr << 9) | tid;
      const float4 y4 = sp[s];                        // coalesced
      if (k == 0) {
        float2 yc0 = make_float2(y4.x, y4.y), yt0 = A[IDX(0)];
        float X0 = yc0.x + yc0.y, XM = yc0.x - yc0.y;
        float T0 = yt0.x + yt0.y, TM = yt0.x - yt0.y;
        float C0 = X0 * T0, CM = XM * TM;
        A[IDX(0)] = make_float2(0.5f * (C0 + CM), 0.5f * (C0 - CM));
        // bin 8192 (self-paired): rev4(8192) == 2
        float2 yc = make_float2(y4.z, y4.w), yt = A[IDX(2)];
        float cr8 = yc.x * yt.x + yc.y * yt.y;
        float ci8 = yc.x * yt.y - yc.y * yt.x;
        A[IDX(2)] = make_float2(cr8, -ci8);
      } else {
        const int p = IDX(rev4_14(k)), q = IDX(rev4_14(FM - k));
        const float2 w = w32[k];                        // e^{-2*pi*i*k/32768}
        // X[k], X[M-k] from Yc (coalesced stash)
        float2 ya = make_float2(y4.x, y4.y), yb = make_float2(y4.z, y4.w);
        float xer = 0.5f * (ya.x + yb.x), xei = 0.5f * (ya.y - yb.y);
        float dr  = 0.5f * (ya.x - yb.x), di  = 0.5f * (ya.y + yb.y);
        float xo_r = di, xo_i = -dr;                    // Xo = -i*D
        float wxr = w.x * xo_r - w.y * xo_i, wxi = w.x * xo_i + w.y * xo_r;
        float Xkr = xer + wxr, Xki = xei + wxi;
        float Xmr = xer - wxr, Xmi = -(xei - wxi);      // X[M-k] = conj(Xe - W*Xo)
        // T[k], T[M-k] from Yt
        float2 ta = A[p], tb2 = A[q];
        float ter = 0.5f * (ta.x + tb2.x), tei = 0.5f * (ta.y - tb2.y);
        float er2 = 0.5f * (ta.x - tb2.x), ei2 = 0.5f * (ta.y + tb2.y);
        float to_r = ei2, to_i = -er2;
        float twr = w.x * to_r - w.y * to_i, twi = w.x * to_i + w.y * to_r;
        float Tkr = ter + twr, Tki = tei + twi;
        float Tmr = ter - twr, Tmi = -(tei - twi);
        // C[k]=X[k]*conj(T[k]); C[M-k]=X[M-k]*conj(T[M-k])
        float Ckr = Xkr * Tkr + Xki * Tki, Cki = Xki * Tkr - Xkr * Tki;
        float Cmr = Xmr * Tmr + Xmi * Tmi, Cmi = Xmi * Tmr - Xmr * Tmi;
        // y'[k] = Ce + i*V*D, V = conj(w)
        float aer = 0.5f * (Ckr + Cmr), aei = 0.5f * (Cki - Cmi);
        float bdr = 0.5f * (Ckr - Cmr), bdi = 0.5f * (Cki + Cmi);
        float cor_ = w.x * bdr + w.y * bdi, coi = w.x * bdi - w.y * bdr;
        A[p] = make_float2(aer - coi, aei + cor_);
        // y'[M-k] = Ce2 + i*(-w)*D2
        float a2r = 0.5f * (Cmr + Ckr), a2i = 0.5f * (Cmi - Cki);
        float d2r = 0.5f * (Cmr - Ckr), d2i = 0.5f * (Cmi + Cki);
        float c2r = -(w.x * d2r - w.y * d2i), c2i = -(w.x * d2i + w.y * d2r);
        A[q] = make_float2(a2r - c2i, a2i + c2r);
      }
    }

    fft_dit4_inv(A, tw, tid);  // A[n] = (cc[2n], cc[2n+1]) * FM

    // argmax with j->np mapping: j<=14336 -> np=j ; (14336,18432) dead ; j>=18432 -> np=j-4095
    unsigned long long pk = 0ull;
    for (int i = tid; i < FM; i += 512) {
      float2 v2 = A[IDX(i)];
      int j0 = 2 * i, j1 = 2 * i + 1;
      if (j0 <= 14336) {
        unsigned long long p = ((unsigned long long)fkey(v2.x) << 32)
                             | (unsigned long long)(0xFFFFFFFFu - (unsigned)j0);
        if (p > pk) pk = p;
      } else if (j0 >= 18432) {
        unsigned long long p = ((unsigned long long)fkey(v2.x) << 32)
                             | (unsigned long long)(0xFFFFFFFFu - (unsigned)(j0 - 4095));
        if (p > pk) pk = p;
      }
      if (j1 <= 14336) {
        unsigned long long p = ((unsigned long long)fkey(v2.y) << 32)
                             | (unsigned long long)(0xFFFFFFFFu - (unsigned)j1);
        if (p > pk) pk = p;
      } else if (j1 >= 18432) {
        unsigned long long p = ((unsigned long long)fkey(v2.y) << 32)
                             | (unsigned long long)(0xFFFFFFFFu - (unsigned)(j1 - 4095));
        if (p > pk) pk = p;
      }
    }
    #pragma unroll
    for (int o = 32; o > 0; o >>= 1) {
      unsigned long long q = __shfl_down(pk, o, 64);
      if (q > pk) pk = q;
    }
    if ((tid & 63) == 0) sbest[tid >> 6] = pk;
    __syncthreads();
    if (tid == 0) {
      #pragma unroll
      for (int i = 1; i < 8; ++i) if (sbest[i] > pk) pk = sbest[i];
      best[b] = pk;
      snp = (int)(0xFFFFFFFFu - (unsigned)(pk & 0xFFFFFFFFull));
    }
    __syncthreads();

    // ===== fused closs: conv row is L2-hot, best is block-local ==============
    {
      const int shift = snp - PADL;
      if (tid < CROP) {
        const int jj = CSTART + tid;
        int pos = jj + shift;
        if (pos < 0) pos += CL; else if (pos >= CL) pos -= CL;
        float d = cr[pos] - tr[jj];
        closs_sum += d * d;
      }
    }
    __syncthreads();
  }

  // ===== fused astf MSE + closs reductions, two atomics per block ============
  #pragma unroll
  for (int o = 32; o > 0; o >>= 1) {
    asum      += __shfl_down(asum, o, 64);
    closs_sum += __shfl_down(closs_sum, o, 64);
  }
  if ((tid & 63) == 0) swsum[tid >> 6] = asum;
  __syncthreads();
  if (tid == 0) {
    float s = 0.f;
    #pragma unroll
    for (int i = 0; i < 8; ++i) s += swsum[i];
    atomicAdd(&acc[0], s);
  }
  __syncthreads();
  if ((tid & 63) == 0) swsum[tid >> 6] = closs_sum;
  __syncthreads();
  if (tid == 0) {
    float s = 0.f;
    #pragma unroll
    for (int i = 0; i < 8; ++i) s += swsum[i];
    atomicAdd(&acc[1], s);
  }
}

// ---- fallback direct path (proven r3 kernels) -------------------------------

__device__ __forceinline__ void taps4(float* acc, const float4 a, const float4 b,
                                      const float4 e) {
  acc[0] = fmaf(a.x, e.x, acc[0]); acc[0] = fmaf(a.y, e.y, acc[0]);
  acc[0] = fmaf(a.z, e.z, acc[0]); acc[0] = fmaf(a.w, e.w, acc[0]);
  acc[1] = fmaf(a.y, e.x, acc[1]); acc[1] = fmaf(a.z, e.y, acc[1]);
  acc[1] = fmaf(a.w, e.z, acc[1]); acc[1] = fmaf(b.x, e.w, acc[1]);
  acc[2] = fmaf(a.z, e.x, acc[2]); acc[2] = fmaf(a.w, e.y, acc[2]);
  acc[2] = fmaf(b.x, e.z, acc[2]); acc[2] = fmaf(b.y, e.w, acc[2]);
  acc[3] = fmaf(a.w, e.x, acc[3]); acc[3] = fmaf(b.x, e.y, acc[3]);
  acc[3] = fmaf(b.y, e.z, acc[3]); acc[3] = fmaf(b.z, e.w, acc[3]);
}

__device__ __forceinline__ float4 gload4(const float* __restrict__ cr, int g) {
  if (g >= 0 && g + 3 < CL) return *(const float4*)(cr + g);
  float4 v;
  int g0 = min(max(g,     0), CL - 1);
  int g1 = min(max(g + 1, 0), CL - 1);
  int g2 = min(max(g + 2, 0), CL - 1);
  int g3 = min(max(g + 3, 0), CL - 1);
  v.x = (g     >= 0 && g     < CL) ? cr[g0] : 0.f;
  v.y = (g + 1 >= 0 && g + 1 < CL) ? cr[g1] : 0.f;
  v.z = (g + 2 >= 0 && g + 2 < CL) ? cr[g2] : 0.f;
  v.w = (g + 3 >= 0 && g + 3 < CL) ? cr[g3] : 0.f;
  return v;
}

__global__ __launch_bounds__(256) void conv_kernel(const float* __restrict__ pred,
                                                   const float* __restrict__ egf,
                                                   float* __restrict__ convbuf) {
  const int b = blockIdx.y;
  const int x = blockIdx.x;
  const int tid = threadIdx.x;
  const float* pb = pred + (size_t)b * L1;
  const float* eg = egf  + (size_t)b * L2;
  float* cr = convbuf + (size_t)b * CROW;

  if (x == 7) {
    float s = 0.f;
    const int k0 = tid * 8;
    #pragma unroll
    for (int j = 0; j < 8; ++j) s += pb[PADL + k0 + j] * eg[k0 + j];
    s = blockReduceSum256(s);
    if (tid == 0) cr[PADL] = s;
    return;
  }

  const int m = x * 2048 + tid * 8;
  const float* cp = pb + m;
  float accA[4] = {0.f,0.f,0.f,0.f};
  float accB[4] = {0.f,0.f,0.f,0.f};
  float4 w0 = *(const float4*)(cp);
  float4 w1 = *(const float4*)(cp + 4);
  float4 w2 = *(const float4*)(cp + 8);

  #pragma unroll 4
  for (int k = 0; k < L2 - 4; k += 4) {
    const float4 e  = *(const float4*)(eg + k);
    const float4 nx = *(const float4*)(cp + k + 12);
    taps4(accA, w0, w1, e);
    taps4(accB, w1, w2, e);
    w0 = w1; w1 = w2; w2 = nx;
  }
  {
    const float4 e = *(const float4*)(eg + (L2 - 4));
    taps4(accA, w0, w1, e);
    taps4(accB, w1, w2, e);
  }

  *(float4*)(cr + m)     = make_float4(accA[0], accA[1], accA[2], accA[3]);
  *(float4*)(cr + m + 4) = make_float4(accB[0], accB[1], accB[2], accB[3]);
}

__global__ __launch_bounds__(256) void cc_kernel(const float* __restrict__ convbuf,
                                                 const float* __restrict__ target,
                                                 unsigned long long* __restrict__ best) {
  __shared__ unsigned long long sbest[4];
  const int b   = blockIdx.y;
  const int m0  = blockIdx.x * 2048;
  const int tid = threadIdx.x;
  const float* cr = convbuf + (size_t)b * CROW;
  const float* tr = target  + (size_t)b * TLEN;
  const int m    = m0 + tid * 8;
  const int gofs = m - PADL;

  float accA[4] = {0.f,0.f,0.f,0.f};
  float accB[4] = {0.f,0.f,0.f,0.f};

  const int t1raw = PADL - m0;
  const int t1    = t1raw > 0 ? t1raw : 0;
  const int t2    = PADL + CL - m0 - 2047;
  int tIntHi      = (t2 - 16) & ~3;
  if (tIntHi > 14332) tIntHi = 14332;
  if (tIntHi < t1)    tIntHi = t1;
  int e0 = (t1raw - 2047) > 0 ? ((t1raw - 2047) & ~3) : 0;
  const int eH = min(TLEN, NCC - m0);

  if (e0 < t1) {
    float4 w0 = gload4(cr, gofs + e0);
    float4 w1 = gload4(cr, gofs + e0 + 4);
    float4 w2 = gload4(cr, gofs + e0 + 8);
    #pragma unroll 2
    for (int t = e0; t < t1; t += 4) {
      const float4 e  = *(const float4*)(tr + t);
      const float4 nx = gload4(cr, gofs + t + 12);
      taps4(accA, w0, w1, e);
      taps4(accB, w1, w2, e);
      w0 = w1; w1 = w2; w2 = nx;
    }
  }

  if (t1 < tIntHi) {
    const float* cp = cr + gofs;
    float4 w0 = *(const float4*)(cp + t1);
    float4 w1 = *(const float4*)(cp + t1 + 4);
    float4 w2 = *(const float4*)(cp + t1 + 8);
    #pragma unroll 4
    for (int t = t1; t < tIntHi; t += 4) {
      const float4 e  = *(const float4*)(tr + t);
      const float4 nx = *(const float4*)(cp + t + 12);
      taps4(accA, w0, w1, e);
      taps4(accB, w1, w2, e);
      w0 = w1; w1 = w2; w2 = nx;
    }
  }

  if (tIntHi < eH) {
    float4 w0 = gload4(cr, gofs + tIntHi);
    float4 w1 = gload4(cr, gofs + tIntHi + 4);
    float4 w2 = gload4(cr, gofs + tIntHi + 8);
    #pragma unroll 2
    for (int t = tIntHi; t < eH; t += 4) {
      float4 e;
      e.x = (t     < TLEN) ? tr[t]     : 0.f;
      e.y = (t + 1 < TLEN) ? tr[t + 1] : 0.f;
      e.z = (t + 2 < TLEN) ? tr[t + 2] : 0.f;
      e.w = (t + 3 < TLEN) ? tr[t + 3] : 0.f;
      const float4 nx = gload4(cr, gofs + t + 12);
      taps4(accA, w0, w1, e);
      taps4(accB, w1, w2, e);
      w0 = w1; w1 = w2; w2 = nx;
    }
  }

  unsigned long long pk = 0ull;
  #pragma unroll
  for (int j = 0; j < 4; ++j) {
    int mm = m + j;
    if (mm < NCC) {
      int np = (mm >= PADL) ? (mm - PADL) : (mm + CL);
      unsigned long long p = ((unsigned long long)fkey(accA[j]) << 32)
                           | (unsigned long long)(0xFFFFFFFFu - (unsigned)np);
      if (p > pk) pk = p;
    }
    mm = m + 4 + j;
    if (mm < NCC) {
      int np = (mm >= PADL) ? (mm - PADL) : (mm + CL);
      unsigned long long p = ((unsigned long long)fkey(accB[j]) << 32)
                           | (unsigned long long)(0xFFFFFFFFu - (unsigned)np);
      if (p > pk) pk = p;
    }
  }
  #pragma unroll
  for (int o = 32; o > 0; o >>= 1) {
    unsigned long long q = __shfl_down(pk, o, 64);
    if (q > pk) pk = q;
  }
  if ((tid & 63) == 0) sbest[tid >> 6] = pk;
  __syncthreads();
  if (tid == 0) {
    #pragma unroll
    for (int i = 1; i < 4; ++i) if (sbest[i] > pk) pk = sbest[i];
    atomicMax(best + b, pk);
  }
}

__global__ void closs_kernel(const float* __restrict__ convbuf,
                             const float* __restrict__ target,
                             const unsigned long long* __restrict__ best,
                             float* __restrict__ acc) {
  const int b = blockIdx.x;
  const int np = (int)(0xFFFFFFFFu - (unsigned)(best[b] & 0xFFFFFFFFull));
  const int shift = np - PADL;
  const int jj = CSTART + threadIdx.x;
  int pos = jj + shift;
  if (pos < 0) pos += CL; else if (pos >= CL) pos -= CL;
  float d = convbuf[(size_t)b * CROW + pos] - target[(size_t)b * TLEN + jj];
  float s = blockReduceSum256(d * d);
  if (threadIdx.x == 0) atomicAdd(&acc[1], s);
}

__global__ void fin_kernel(const float* __restrict__ acc, float* __restrict__ out) {
  if (threadIdx.x == 0 && blockIdx.x == 0) {
    float la = acc[0] / (float)((long)BB * L1);
    float lc = acc[1] / (float)(BB * CROP);
    out[0] = la + lc;
    out[1] = la;
    out[2] = lc;
  }
}

// ---- launch -----------------------------------------------------------------

extern "C" void kernel_launch(void* const* d_in, const int* in_sizes, int n_in,
                              void* d_out, int out_size, void* d_ws, size_t ws_size,
                              hipStream_t stream) {
  (void)in_sizes; (void)n_in; (void)out_size;
  const float* pred   = (const float*)d_in[0];
  const float* truea  = (const float*)d_in[1];
  const float* egf    = (const float*)d_in[2];
  const float* target = (const float*)d_in[3];
  float* out = (float*)d_out;

  char* ws = (char*)d_ws;
  const size_t off_best = (size_t)BB * CROW * 4;          // 29,368,320
  const size_t off_acc  = off_best + (size_t)BB * 8;
  const size_t off_tw   = off_acc + 256;
  const size_t off_w32  = off_tw + (size_t)FM * 8;
  const size_t off_spec = off_w32 + (size_t)8192 * 8;
  const size_t needed   = off_spec + (size_t)256 * FM * 8; // ~63.1 MB

  float* convbuf            = (float*)ws;
  unsigned long long* best  = (unsigned long long*)(ws + off_best);
  float* acc                = (float*)(ws + off_acc);
  float2* tw                = (float2*)(ws + off_tw);
  float2* w32               = (float2*)(ws + off_w32);
  float4* spec              = (float4*)(ws + off_spec);

  init_kernel<<<2, 256, 0, stream>>>(best, acc);

  if (ws_size >= needed) {
    twid_kernel<<<64, 256, 0, stream>>>(tw, w32);
    pipefft_kernel<<<BB / 2, 512, 0, stream>>>(pred, truea, egf, target, tw, w32,
                                               convbuf, spec, best, acc);
    fin_kernel<<<1, 64, 0, stream>>>(acc, out);
  } else {
    astf_kernel<<<1024, 256, 0, stream>>>(pred, truea, acc);
    conv_kernel<<<dim3(8, BB), 256, 0, stream>>>(pred, egf, convbuf);
    cc_kernel<<<dim3(15, BB), 256, 0, stream>>>(convbuf, target, best);
    closs_kernel<<<dim3(BB), 256, 0, stream>>>(convbuf, target, best, acc);
    fin_kernel<<<1, 64, 0, stream>>>(acc, out);
  }
}